// Round 1
// baseline (3713.569 us; speedup 1.0000x reference)
//
#include <hip/hip_runtime.h>

#define NN 50000
#define NE 500000
#define HID 128
#define LAYERS 3
#define RELS 8
#define BASES 30
#define GRAPHS 16
#define CLASSES 8
#define EPSV 1e-5f
#define KTOT (HID * (RELS + 1))   // 1152

// ---------------- Wcat: [L][1152][128]  rows 0..127 = root, rows 128+r*128+k = W_r[k][:]
__global__ void build_wcat(const float* __restrict__ basis, const float* __restrict__ comp,
                           const float* __restrict__ root, float* __restrict__ wcat) {
    int idx = blockIdx.x * blockDim.x + threadIdx.x;
    if (idx >= LAYERS * KTOT * HID) return;
    int j = idx & (HID - 1);
    int rowl = idx >> 7;            // (l,row)
    int l = rowl / KTOT;
    int row = rowl % KTOT;
    float v;
    if (row < HID) {
        v = root[((size_t)l * HID + row) * HID + j];
    } else {
        int r = (row - HID) >> 7;
        int k = (row - HID) & (HID - 1);
        const float* cp = comp + ((size_t)l * RELS + r) * BASES;
        float s = 0.f;
        for (int b = 0; b < BASES; ++b)
            s += cp[b] * basis[(((size_t)(l * BASES + b)) * HID + k) * HID + j];
        v = s;
    }
    wcat[idx] = v;
}

// ---------------- BN1 (eval mode)
__global__ void bn1_kernel(const float* __restrict__ x, const float* __restrict__ gamma,
                           const float* __restrict__ beta, const float* __restrict__ mean,
                           const float* __restrict__ var, float* __restrict__ h) {
    int idx = blockIdx.x * blockDim.x + threadIdx.x;
    if (idx >= NN * HID) return;
    int f = idx & (HID - 1);
    h[idx] = (x[idx] - mean[f]) * rsqrtf(var[f] + EPSV) * gamma[f] + beta[f];
}

// ---------------- degree count per (dst, rel)
__global__ void deg_kernel(const int* __restrict__ ei, const int* __restrict__ ea,
                           float* __restrict__ deg) {
    int e = blockIdx.x * blockDim.x + threadIdx.x;
    if (e >= NE) return;
    int dst = ei[NE + e];
    atomicAdd(&deg[(size_t)dst * RELS + ea[e]], 1.0f);
}

__global__ void invdeg_kernel(float* __restrict__ deg) {
    int i = blockIdx.x * blockDim.x + threadIdx.x;
    if (i >= NN * RELS) return;
    deg[i] = 1.0f / fmaxf(deg[i], 1.0f);
}

// ---------------- scatter: agg[dst][r][:] += h[src][:] * invdeg[dst][r]
// 32 lanes per edge (float4 per lane), 8 edges per 256-thread block
__global__ __launch_bounds__(256) void scatter_kernel(const int* __restrict__ ei,
                                                      const int* __restrict__ ea,
                                                      const float* __restrict__ h,
                                                      const float* __restrict__ invdeg,
                                                      float* __restrict__ agg) {
    int e = blockIdx.x * 8 + (threadIdx.x >> 5);
    if (e >= NE) return;
    int f = (threadIdx.x & 31) << 2;
    int src = ei[e];
    int dst = ei[NE + e];
    int r = ea[e];
    float s = invdeg[(size_t)dst * RELS + r];
    float4 hv = *(const float4*)&h[(size_t)src * HID + f];
    float* ap = &agg[((size_t)dst * RELS + r) * HID + f];
    atomicAdd(ap + 0, hv.x * s);
    atomicAdd(ap + 1, hv.y * s);
    atomicAdd(ap + 2, hv.z * s);
    atomicAdd(ap + 3, hv.w * s);
}

// ---------------- fused GEMM: out = relu([h | agg] @ Wcat + bias)
// M-tile 128 x full N=128, BK=16, 256 threads, 8x8 microtile
__global__ __launch_bounds__(256) void gemm_relu(const float* __restrict__ h,
                                                 const float* __restrict__ agg,
                                                 const float* __restrict__ w,
                                                 const float* __restrict__ bias,
                                                 float* __restrict__ out) {
    __shared__ float As[16][132];   // transposed A tile, padded (132%32=4 -> 2-way store alias, free)
    __shared__ float Bs[16][128];
    int tid = threadIdx.x;
    int row0 = blockIdx.x * 128;
    int tr = (tid >> 4) << 3;
    int tc = (tid & 15) << 3;
    float acc[8][8];
#pragma unroll
    for (int i = 0; i < 8; ++i)
#pragma unroll
        for (int j = 0; j < 8; ++j) acc[i][j] = 0.f;

    for (int k0 = 0; k0 < KTOT; k0 += 16) {
#pragma unroll
        for (int ld = 0; ld < 2; ++ld) {
            int idx = tid + ld * 256;          // 0..511
            // A: 128 rows x 16 k = 512 float4
            int r  = idx >> 2;
            int kq = (idx & 3) << 2;
            int grow = row0 + r;
            int k = k0 + kq;
            float4 v = make_float4(0.f, 0.f, 0.f, 0.f);
            if (grow < NN) {
                const float* src = (k < HID) ? (h + (size_t)grow * HID + k)
                                             : (agg + (size_t)grow * (RELS * HID) + (k - HID));
                v = *(const float4*)src;
            }
            As[kq + 0][r] = v.x;
            As[kq + 1][r] = v.y;
            As[kq + 2][r] = v.z;
            As[kq + 3][r] = v.w;
            // B: 16 k x 128 j = 512 float4
            int kk = idx >> 5;
            int jq = (idx & 31) << 2;
            *(float4*)&Bs[kk][jq] = *(const float4*)&w[(size_t)(k0 + kk) * HID + jq];
        }
        __syncthreads();
#pragma unroll
        for (int kk = 0; kk < 16; ++kk) {
            float a[8], b[8];
            *(float4*)&a[0] = *(const float4*)&As[kk][tr];
            *(float4*)&a[4] = *(const float4*)&As[kk][tr + 4];
            *(float4*)&b[0] = *(const float4*)&Bs[kk][tc];
            *(float4*)&b[4] = *(const float4*)&Bs[kk][tc + 4];
#pragma unroll
            for (int i = 0; i < 8; ++i)
#pragma unroll
                for (int j = 0; j < 8; ++j) acc[i][j] += a[i] * b[j];
        }
        __syncthreads();
    }
#pragma unroll
    for (int i = 0; i < 8; ++i) {
        int grow = row0 + tr + i;
        if (grow >= NN) break;
#pragma unroll
        for (int j = 0; j < 8; ++j) {
            float v = acc[i][j] + bias[tc + j];
            out[(size_t)grow * HID + tc + j] = fmaxf(v, 0.f);
        }
    }
}

// ---------------- global mean pool (stage in LDS, then global atomics)
__global__ __launch_bounds__(256) void pool_kernel(const float* __restrict__ h,
                                                   const int* __restrict__ batch,
                                                   float* __restrict__ psum,
                                                   float* __restrict__ pcnt) {
    __shared__ float ls[GRAPHS * HID];
    __shared__ float lc[GRAPHS];
    int tid = threadIdx.x;
    for (int i = tid; i < GRAPHS * HID; i += 256) ls[i] = 0.f;
    if (tid < GRAPHS) lc[tid] = 0.f;
    __syncthreads();
    int base = blockIdx.x * 512;
    int f = tid & 127;
    int sub = tid >> 7;
    for (int it = 0; it < 256; ++it) {
        int node = base + it * 2 + sub;
        if (node < NN) {
            int g = batch[node];
            atomicAdd(&ls[g * HID + f], h[(size_t)node * HID + f]);
            if (f == 0) atomicAdd(&lc[g], 1.0f);
        }
    }
    __syncthreads();
    for (int i = tid; i < GRAPHS * HID; i += 256) atomicAdd(&psum[i], ls[i]);
    if (tid < GRAPHS) atomicAdd(&pcnt[tid], lc[tid]);
}

// ---------------- head: BN2, graph-mean, fc1+relu, fc2, log_softmax
__global__ void head_kernel(const float* __restrict__ psum, const float* __restrict__ pcnt,
                            const float* __restrict__ g2, const float* __restrict__ b2,
                            const float* __restrict__ m2, const float* __restrict__ v2,
                            const float* __restrict__ fc1w, const float* __restrict__ fc1b,
                            const float* __restrict__ fc2w, const float* __restrict__ fc2b,
                            float* __restrict__ out) {
    __shared__ float v[HID];
    __shared__ float u[HID];
    __shared__ float lg[CLASSES];
    int j = threadIdx.x;   // 128 threads
    float acc = 0.f;
    for (int g = 0; g < GRAPHS; ++g) {
        float val = psum[g * HID + j] / fmaxf(pcnt[g], 1.0f);
        val = (val - m2[j]) * rsqrtf(v2[j] + EPSV) * g2[j] + b2[j];
        acc += val;
    }
    v[j] = fmaxf(acc / (float)GRAPHS, 0.f);
    __syncthreads();
    float s = fc1b[j];
    for (int k = 0; k < HID; ++k) s += v[k] * fc1w[k * HID + j];
    u[j] = fmaxf(s, 0.f);
    __syncthreads();
    if (j < CLASSES) {
        float t = fc2b[j];
        for (int k = 0; k < HID; ++k) t += u[k] * fc2w[k * CLASSES + j];
        lg[j] = t;
    }
    __syncthreads();
    if (j < CLASSES) {
        float mx = lg[0];
        for (int c = 1; c < CLASSES; ++c) mx = fmaxf(mx, lg[c]);
        float se = 0.f;
        for (int c = 0; c < CLASSES; ++c) se += expf(lg[c] - mx);
        out[j] = lg[j] - mx - logf(se);
    }
}

extern "C" void kernel_launch(void* const* d_in, const int* in_sizes, int n_in,
                              void* d_out, int out_size, void* d_ws, size_t ws_size,
                              hipStream_t stream) {
    const float* x     = (const float*)d_in[0];
    const int*   ei    = (const int*)d_in[1];
    const int*   ea    = (const int*)d_in[2];
    const int*   batch = (const int*)d_in[3];
    const float* bn1g  = (const float*)d_in[4];
    const float* bn1b  = (const float*)d_in[5];
    const float* bn1m  = (const float*)d_in[6];
    const float* bn1v  = (const float*)d_in[7];
    const float* basis = (const float*)d_in[8];
    const float* comp  = (const float*)d_in[9];
    const float* root  = (const float*)d_in[10];
    const float* bias  = (const float*)d_in[11];
    const float* bn2g  = (const float*)d_in[12];
    const float* bn2b  = (const float*)d_in[13];
    const float* bn2m  = (const float*)d_in[14];
    const float* bn2v  = (const float*)d_in[15];
    const float* fc1w  = (const float*)d_in[16];
    const float* fc1b  = (const float*)d_in[17];
    const float* fc2w  = (const float*)d_in[18];
    const float* fc2b  = (const float*)d_in[19];

    float* ws = (float*)d_ws;
    size_t off = 0;
    float* wcat = ws + off; off += (size_t)LAYERS * KTOT * HID;   // 442368
    float* h    = ws + off; off += (size_t)NN * HID;              // 6.4M
    float* hn   = ws + off; off += (size_t)NN * HID;              // 6.4M
    float* agg  = ws + off; off += (size_t)NN * RELS * HID;       // 51.2M
    float* deg  = ws + off; off += (size_t)NN * RELS;             // 400k
    float* psum = ws + off; off += (size_t)GRAPHS * HID;          // 2048
    float* pcnt = ws + off; off += (size_t)GRAPHS;                // 16
    if (ws_size < off * sizeof(float)) return;                    // ws too small: bail (will fail validation loudly)

    hipMemsetAsync(psum, 0, (GRAPHS * HID + GRAPHS) * sizeof(float), stream);
    build_wcat<<<(LAYERS * KTOT * HID + 255) / 256, 256, 0, stream>>>(basis, comp, root, wcat);
    bn1_kernel<<<(NN * HID + 255) / 256, 256, 0, stream>>>(x, bn1g, bn1b, bn1m, bn1v, h);

    for (int l = 0; l < LAYERS; ++l) {
        hipMemsetAsync(deg, 0, (size_t)NN * RELS * sizeof(float), stream);
        hipMemsetAsync(agg, 0, (size_t)NN * RELS * HID * sizeof(float), stream);
        deg_kernel<<<(NE + 255) / 256, 256, 0, stream>>>(ei, ea, deg);
        invdeg_kernel<<<(NN * RELS + 255) / 256, 256, 0, stream>>>(deg);
        scatter_kernel<<<(NE + 7) / 8, 256, 0, stream>>>(ei, ea, h, deg, agg);
        gemm_relu<<<(NN + 127) / 128, 256, 0, stream>>>(
            h, agg, wcat + (size_t)l * KTOT * HID, bias + (size_t)l * HID, hn);
        float* t = h; h = hn; hn = t;
    }

    pool_kernel<<<(NN + 511) / 512, 256, 0, stream>>>(h, batch, psum, pcnt);
    head_kernel<<<1, 128, 0, stream>>>(psum, pcnt, bn2g, bn2b, bn2m, bn2v,
                                       fc1w, fc1b, fc2w, fc2b, (float*)d_out);
}

// Round 2
// 3284.274 us; speedup vs baseline: 1.1307x; 1.1307x over previous
//
#include <hip/hip_runtime.h>
#include <hip/hip_bf16.h>

#define NN 50000
#define NE 500000
#define HID 128
#define LAYERS 3
#define RELS 8
#define BASES 30
#define GRAPHS 16
#define CLASSES 8
#define EPSV 1e-5f
#define NOUT (HID * (RELS + 1))   // 1152 = GEMM N dimension (root + 8 relations)

__device__ __forceinline__ float bf2f(unsigned short u) {
    union { unsigned int i; float f; } x; x.i = ((unsigned int)u) << 16; return x.f;
}

// ---------------- WcatT: [L][128 f][1152 n], n = c*128+j; c=0 root, c=1+r -> W_r[f][j]
__global__ void build_wcat(const float* __restrict__ basis, const float* __restrict__ comp,
                           const float* __restrict__ root, float* __restrict__ wcat) {
    int idx = blockIdx.x * blockDim.x + threadIdx.x;
    if (idx >= LAYERS * HID * NOUT) return;
    int n = idx % NOUT;
    int fl = idx / NOUT;
    int f = fl & (HID - 1);
    int l = fl >> 7;
    int c = n >> 7;
    int j = n & (HID - 1);
    float v;
    if (c == 0) {
        v = root[((size_t)l * HID + f) * HID + j];
    } else {
        int r = c - 1;
        const float* cp = comp + ((size_t)l * RELS + r) * BASES;
        float s = 0.f;
        for (int b = 0; b < BASES; ++b)
            s += cp[b] * basis[(((size_t)(l * BASES + b)) * HID + f) * HID + j];
        v = s;
    }
    wcat[idx] = v;
}

// ---------------- BN1 (eval mode)
__global__ void bn1_kernel(const float* __restrict__ x, const float* __restrict__ gamma,
                           const float* __restrict__ beta, const float* __restrict__ mean,
                           const float* __restrict__ var, float* __restrict__ h) {
    int idx = blockIdx.x * blockDim.x + threadIdx.x;
    if (idx >= NN * HID) return;
    int f = idx & (HID - 1);
    h[idx] = (x[idx] - mean[f]) * rsqrtf(var[f] + EPSV) * gamma[f] + beta[f];
}

// ---------------- degree count per (dst, rel) — edge-structure-invariant, once per call
__global__ void deg_kernel(const int* __restrict__ ei, const int* __restrict__ ea,
                           float* __restrict__ deg) {
    int e = blockIdx.x * blockDim.x + threadIdx.x;
    if (e >= NE) return;
    int dst = ei[NE + e];
    atomicAdd(&deg[(size_t)dst * RELS + ea[e]], 1.0f);
}

__global__ void invdeg_kernel(float* __restrict__ deg) {
    int i = blockIdx.x * blockDim.x + threadIdx.x;
    if (i >= NN * RELS) return;
    deg[i] = 1.0f / fmaxf(deg[i], 1.0f);
}

// ---------------- GEMM: [h] @ WcatT -> col-tile 0: hn (fp32, +bias); col-tiles 1..8: xwb (bf16)
// M=50000, N=1152, K=128. Block: 128x128 tile, BK=16, 256 threads, 8x8 microtile.
template <bool RELU>
__global__ __launch_bounds__(256) void gemm_xw(const float* __restrict__ a_in,
                                               const float* __restrict__ w,
                                               const float* __restrict__ bias,
                                               float* __restrict__ hn,
                                               __hip_bfloat16* __restrict__ xwb) {
    __shared__ float As[16][132];   // transposed A tile (2-way store alias = free)
    __shared__ float Bs[16][128];
    int tid = threadIdx.x;
    int row0 = blockIdx.x * 128;
    int n0 = blockIdx.y * 128;
    int tr = (tid >> 4) << 3;
    int tc = (tid & 15) << 3;
    float acc[8][8];
#pragma unroll
    for (int i = 0; i < 8; ++i)
#pragma unroll
        for (int j = 0; j < 8; ++j) acc[i][j] = 0.f;

    for (int k0 = 0; k0 < HID; k0 += 16) {
#pragma unroll
        for (int ld = 0; ld < 2; ++ld) {
            int idx = tid + ld * 256;          // 0..511
            // A: 128 rows x 16 k  (512 float4)
            int r  = idx >> 2;
            int kq = (idx & 3) << 2;
            int grow = row0 + r;
            float4 v = make_float4(0.f, 0.f, 0.f, 0.f);
            if (grow < NN) v = *(const float4*)&a_in[(size_t)grow * HID + k0 + kq];
            if (RELU) {
                v.x = fmaxf(v.x, 0.f); v.y = fmaxf(v.y, 0.f);
                v.z = fmaxf(v.z, 0.f); v.w = fmaxf(v.w, 0.f);
            }
            As[kq + 0][r] = v.x;
            As[kq + 1][r] = v.y;
            As[kq + 2][r] = v.z;
            As[kq + 3][r] = v.w;
            // B: 16 k x 128 n  (512 float4), row stride NOUT
            int kk = idx >> 5;
            int jq = (idx & 31) << 2;
            *(float4*)&Bs[kk][jq] = *(const float4*)&w[(size_t)(k0 + kk) * NOUT + n0 + jq];
        }
        __syncthreads();
#pragma unroll
        for (int kk = 0; kk < 16; ++kk) {
            float a[8], b[8];
            *(float4*)&a[0] = *(const float4*)&As[kk][tr];
            *(float4*)&a[4] = *(const float4*)&As[kk][tr + 4];
            *(float4*)&b[0] = *(const float4*)&Bs[kk][tc];
            *(float4*)&b[4] = *(const float4*)&Bs[kk][tc + 4];
#pragma unroll
            for (int i = 0; i < 8; ++i)
#pragma unroll
                for (int j = 0; j < 8; ++j) acc[i][j] += a[i] * b[j];
        }
        __syncthreads();
    }

    if (blockIdx.y == 0) {
        // root columns: fp32 out + bias (messages atomically added later; relu on next load)
#pragma unroll
        for (int i = 0; i < 8; ++i) {
            int grow = row0 + tr + i;
            if (grow >= NN) break;
#pragma unroll
            for (int j = 0; j < 8; ++j)
                hn[(size_t)grow * HID + tc + j] = acc[i][j] + bias[tc + j];
        }
    } else {
        int cbase = (blockIdx.y - 1) * 128;    // column within xwb row of width 1024
#pragma unroll
        for (int i = 0; i < 8; ++i) {
            int grow = row0 + tr + i;
            if (grow >= NN) break;
#pragma unroll
            for (int j = 0; j < 8; ++j)
                xwb[(size_t)grow * (RELS * HID) + cbase + tc + j] = __float2bfloat16(acc[i][j]);
        }
    }
}

// ---------------- scatter: hn[dst][f] += xwb[src][r][f] * invdeg[dst][r]
// 32 lanes per edge (bf16x4 per lane), 8 edges per 256-thread block; target is 25.6MB (L2)
__global__ __launch_bounds__(256) void scatter_kernel(const int* __restrict__ ei,
                                                      const int* __restrict__ ea,
                                                      const __hip_bfloat16* __restrict__ xwb,
                                                      const float* __restrict__ invdeg,
                                                      float* __restrict__ hn) {
    int e = blockIdx.x * 8 + (threadIdx.x >> 5);
    if (e >= NE) return;
    int f = (threadIdx.x & 31) << 2;
    int src = ei[e];
    int dst = ei[NE + e];
    int r = ea[e];
    float s = invdeg[(size_t)dst * RELS + r];
    const unsigned short* xp = (const unsigned short*)xwb + (size_t)src * (RELS * HID) + r * HID + f;
    ushort4 u = *(const ushort4*)xp;
    float* op = hn + (size_t)dst * HID + f;
    atomicAdd(op + 0, bf2f(u.x) * s);
    atomicAdd(op + 1, bf2f(u.y) * s);
    atomicAdd(op + 2, bf2f(u.z) * s);
    atomicAdd(op + 3, bf2f(u.w) * s);
}

// ---------------- global mean pool (relu on load; stage in LDS, then global atomics)
__global__ __launch_bounds__(256) void pool_kernel(const float* __restrict__ h,
                                                   const int* __restrict__ batch,
                                                   float* __restrict__ psum,
                                                   float* __restrict__ pcnt) {
    __shared__ float ls[GRAPHS * HID];
    __shared__ float lc[GRAPHS];
    int tid = threadIdx.x;
    for (int i = tid; i < GRAPHS * HID; i += 256) ls[i] = 0.f;
    if (tid < GRAPHS) lc[tid] = 0.f;
    __syncthreads();
    int base = blockIdx.x * 512;
    int f = tid & 127;
    int sub = tid >> 7;
    for (int it = 0; it < 256; ++it) {
        int node = base + it * 2 + sub;
        if (node < NN) {
            int g = batch[node];
            atomicAdd(&ls[g * HID + f], fmaxf(h[(size_t)node * HID + f], 0.f));
            if (f == 0) atomicAdd(&lc[g], 1.0f);
        }
    }
    __syncthreads();
    for (int i = tid; i < GRAPHS * HID; i += 256) atomicAdd(&psum[i], ls[i]);
    if (tid < GRAPHS) atomicAdd(&pcnt[tid], lc[tid]);
}

// ---------------- head: BN2, graph-mean, fc1+relu, fc2, log_softmax
__global__ void head_kernel(const float* __restrict__ psum, const float* __restrict__ pcnt,
                            const float* __restrict__ g2, const float* __restrict__ b2,
                            const float* __restrict__ m2, const float* __restrict__ v2,
                            const float* __restrict__ fc1w, const float* __restrict__ fc1b,
                            const float* __restrict__ fc2w, const float* __restrict__ fc2b,
                            float* __restrict__ out) {
    __shared__ float v[HID];
    __shared__ float u[HID];
    __shared__ float lg[CLASSES];
    int j = threadIdx.x;   // 128 threads
    float acc = 0.f;
    for (int g = 0; g < GRAPHS; ++g) {
        float val = psum[g * HID + j] / fmaxf(pcnt[g], 1.0f);
        val = (val - m2[j]) * rsqrtf(v2[j] + EPSV) * g2[j] + b2[j];
        acc += val;
    }
    v[j] = fmaxf(acc / (float)GRAPHS, 0.f);
    __syncthreads();
    float s = fc1b[j];
    for (int k = 0; k < HID; ++k) s += v[k] * fc1w[k * HID + j];
    u[j] = fmaxf(s, 0.f);
    __syncthreads();
    if (j < CLASSES) {
        float t = fc2b[j];
        for (int k = 0; k < HID; ++k) t += u[k] * fc2w[k * CLASSES + j];
        lg[j] = t;
    }
    __syncthreads();
    if (j < CLASSES) {
        float mx = lg[0];
        for (int c = 1; c < CLASSES; ++c) mx = fmaxf(mx, lg[c]);
        float se = 0.f;
        for (int c = 0; c < CLASSES; ++c) se += expf(lg[c] - mx);
        out[j] = lg[j] - mx - logf(se);
    }
}

extern "C" void kernel_launch(void* const* d_in, const int* in_sizes, int n_in,
                              void* d_out, int out_size, void* d_ws, size_t ws_size,
                              hipStream_t stream) {
    const float* x     = (const float*)d_in[0];
    const int*   ei    = (const int*)d_in[1];
    const int*   ea    = (const int*)d_in[2];
    const int*   batch = (const int*)d_in[3];
    const float* bn1g  = (const float*)d_in[4];
    const float* bn1b  = (const float*)d_in[5];
    const float* bn1m  = (const float*)d_in[6];
    const float* bn1v  = (const float*)d_in[7];
    const float* basis = (const float*)d_in[8];
    const float* comp  = (const float*)d_in[9];
    const float* root  = (const float*)d_in[10];
    const float* bias  = (const float*)d_in[11];
    const float* bn2g  = (const float*)d_in[12];
    const float* bn2b  = (const float*)d_in[13];
    const float* bn2m  = (const float*)d_in[14];
    const float* bn2v  = (const float*)d_in[15];
    const float* fc1w  = (const float*)d_in[16];
    const float* fc1b  = (const float*)d_in[17];
    const float* fc2w  = (const float*)d_in[18];
    const float* fc2b  = (const float*)d_in[19];

    float* ws = (float*)d_ws;
    size_t off = 0;
    float* wcat = ws + off; off += (size_t)LAYERS * HID * NOUT;   // 442368
    float* h0   = ws + off; off += (size_t)NN * HID;              // 6.4M
    float* h1   = ws + off; off += (size_t)NN * HID;              // 6.4M
    float* deg  = ws + off; off += (size_t)NN * RELS;             // 400k
    float* psum = ws + off; off += (size_t)GRAPHS * HID + GRAPHS; // 2064
    float* pcnt = psum + GRAPHS * HID;
    __hip_bfloat16* xwb = (__hip_bfloat16*)(ws + off);
    off += (size_t)NN * RELS * HID / 2;                           // 25.6M float-equiv (bf16)
    if (ws_size < off * sizeof(float)) return;

    hipMemsetAsync(psum, 0, (GRAPHS * HID + GRAPHS) * sizeof(float), stream);
    hipMemsetAsync(deg, 0, (size_t)NN * RELS * sizeof(float), stream);
    build_wcat<<<(LAYERS * HID * NOUT + 255) / 256, 256, 0, stream>>>(basis, comp, root, wcat);
    bn1_kernel<<<(NN * HID + 255) / 256, 256, 0, stream>>>(x, bn1g, bn1b, bn1m, bn1v, h0);
    deg_kernel<<<(NE + 255) / 256, 256, 0, stream>>>(ei, ea, deg);
    invdeg_kernel<<<(NN * RELS + 255) / 256, 256, 0, stream>>>(deg);

    dim3 ggrid((NN + 127) / 128, (RELS + 1));
    float* hin = h0;
    float* hout = h1;
    for (int l = 0; l < LAYERS; ++l) {
        const float* wl = wcat + (size_t)l * HID * NOUT;
        const float* bl = bias + (size_t)l * HID;
        if (l == 0)
            gemm_xw<false><<<ggrid, 256, 0, stream>>>(hin, wl, bl, hout, xwb);
        else
            gemm_xw<true><<<ggrid, 256, 0, stream>>>(hin, wl, bl, hout, xwb);
        scatter_kernel<<<(NE + 7) / 8, 256, 0, stream>>>(ei, ea, xwb, deg, hout);
        float* t = hin; hin = hout; hout = t;
    }

    pool_kernel<<<(NN + 511) / 512, 256, 0, stream>>>(hin, batch, psum, pcnt);
    head_kernel<<<1, 128, 0, stream>>>(psum, pcnt, bn2g, bn2b, bn2m, bn2v,
                                       fc1w, fc1b, fc2w, fc2b, (float*)d_out);
}

// Round 3
// 1012.117 us; speedup vs baseline: 3.6691x; 3.2450x over previous
//
#include <hip/hip_runtime.h>
#include <hip/hip_bf16.h>

#define NN 50000
#define NE 500000
#define HID 128
#define LAYERS 3
#define RELS 8
#define BASES 30
#define GRAPHS 16
#define CLASSES 8
#define EPSV 1e-5f
#define NOUT (HID * (RELS + 1))   // 1152 = GEMM N dimension (root + 8 relations)
#define SCAN_CHUNK 1024
#define SCAN_NBLK ((NN + SCAN_CHUNK - 1) / SCAN_CHUNK)   // 49

__device__ __forceinline__ float bf2f(unsigned short u) {
    union { unsigned int i; float f; } x; x.i = ((unsigned int)u) << 16; return x.f;
}

// ---------------- WcatT: [L][128 f][1152 n], n = c*128+j; c=0 root, c=1+r -> W_r[f][j]
__global__ void build_wcat(const float* __restrict__ basis, const float* __restrict__ comp,
                           const float* __restrict__ root, float* __restrict__ wcat) {
    int idx = blockIdx.x * blockDim.x + threadIdx.x;
    if (idx >= LAYERS * HID * NOUT) return;
    int n = idx % NOUT;
    int fl = idx / NOUT;
    int f = fl & (HID - 1);
    int l = fl >> 7;
    int c = n >> 7;
    int j = n & (HID - 1);
    float v;
    if (c == 0) {
        v = root[((size_t)l * HID + f) * HID + j];
    } else {
        int r = c - 1;
        const float* cp = comp + ((size_t)l * RELS + r) * BASES;
        float s = 0.f;
        for (int b = 0; b < BASES; ++b)
            s += cp[b] * basis[(((size_t)(l * BASES + b)) * HID + f) * HID + j];
        v = s;
    }
    wcat[idx] = v;
}

// ---------------- BN1 (eval mode)
__global__ void bn1_kernel(const float* __restrict__ x, const float* __restrict__ gamma,
                           const float* __restrict__ beta, const float* __restrict__ mean,
                           const float* __restrict__ var, float* __restrict__ h) {
    int idx = blockIdx.x * blockDim.x + threadIdx.x;
    if (idx >= NN * HID) return;
    int f = idx & (HID - 1);
    h[idx] = (x[idx] - mean[f]) * rsqrtf(var[f] + EPSV) * gamma[f] + beta[f];
}

// ---------------- degree count per (dst, rel)
__global__ void deg_kernel(const int* __restrict__ ei, const int* __restrict__ ea,
                           float* __restrict__ deg) {
    int e = blockIdx.x * blockDim.x + threadIdx.x;
    if (e >= NE) return;
    int dst = ei[NE + e];
    atomicAdd(&deg[(size_t)dst * RELS + ea[e]], 1.0f);
}

// degi[n] = total degree (int) — MUST run before invdeg overwrites deg
__global__ void degi_kernel(const float* __restrict__ deg, int* __restrict__ degi) {
    int n = blockIdx.x * blockDim.x + threadIdx.x;
    if (n >= NN) return;
    float s = 0.f;
#pragma unroll
    for (int r = 0; r < RELS; ++r) s += deg[(size_t)n * RELS + r];
    degi[n] = (int)(s + 0.5f);
}

__global__ void invdeg_kernel(float* __restrict__ deg) {
    int i = blockIdx.x * blockDim.x + threadIdx.x;
    if (i >= NN * RELS) return;
    deg[i] = 1.0f / fmaxf(deg[i], 1.0f);
}

// ---------------- exclusive scan of degi -> rowptr (3-phase)
__global__ __launch_bounds__(256) void scan_partial(const int* __restrict__ degi,
                                                    int* __restrict__ rowptr,
                                                    int* __restrict__ bsum) {
    __shared__ int ssc[256];
    int t = threadIdx.x;
    int base = blockIdx.x * SCAN_CHUNK + t * 4;
    int v[4];
#pragma unroll
    for (int j = 0; j < 4; ++j) v[j] = (base + j < NN) ? degi[base + j] : 0;
    int tsum = v[0] + v[1] + v[2] + v[3];
    ssc[t] = tsum;
    __syncthreads();
    for (int ofs = 1; ofs < 256; ofs <<= 1) {
        int add = (t >= ofs) ? ssc[t - ofs] : 0;
        __syncthreads();
        ssc[t] += add;
        __syncthreads();
    }
    int excl = ssc[t] - tsum;
    int e = 0;
#pragma unroll
    for (int j = 0; j < 4; ++j) {
        if (base + j < NN) rowptr[base + j] = excl + e;
        e += v[j];
    }
    if (t == 255) bsum[blockIdx.x] = ssc[255];
}

__global__ void scan_bsum(int* __restrict__ bsum) {
    if (threadIdx.x == 0) {
        int acc = 0;
        for (int b = 0; b < SCAN_NBLK; ++b) { int v = bsum[b]; bsum[b] = acc; acc += v; }
    }
}

__global__ __launch_bounds__(256) void scan_add(int* __restrict__ rowptr,
                                                const int* __restrict__ bsum) {
    int i = blockIdx.x * blockDim.x + threadIdx.x;
    if (i < NN) rowptr[i] += bsum[i >> 10];
    if (i == 0) rowptr[NN] = NE;
}

// ---------------- fill CSR: epk[slot] = src | (r<<20); escale[slot] = invdeg[dst][r]
__global__ void fill_kernel(const int* __restrict__ ei, const int* __restrict__ ea,
                            const int* __restrict__ rowptr, const float* __restrict__ invdeg,
                            int* __restrict__ fillcnt, int* __restrict__ epk,
                            float* __restrict__ escale) {
    int e = blockIdx.x * blockDim.x + threadIdx.x;
    if (e >= NE) return;
    int src = ei[e];
    int dst = ei[NE + e];
    int r = ea[e];
    int pos = atomicAdd(&fillcnt[dst], 1);
    int slot = rowptr[dst] + pos;
    epk[slot] = src | (r << 20);
    escale[slot] = invdeg[(size_t)dst * RELS + r];
}

// ---------------- GEMM: [h] @ WcatT -> col-tile 0: hn (fp32, +bias); col-tiles 1..8: xwb (bf16)
template <bool RELU>
__global__ __launch_bounds__(256) void gemm_xw(const float* __restrict__ a_in,
                                               const float* __restrict__ w,
                                               const float* __restrict__ bias,
                                               float* __restrict__ hn,
                                               __hip_bfloat16* __restrict__ xwb) {
    __shared__ float As[16][132];
    __shared__ float Bs[16][128];
    int tid = threadIdx.x;
    int row0 = blockIdx.x * 128;
    int n0 = blockIdx.y * 128;
    int tr = (tid >> 4) << 3;
    int tc = (tid & 15) << 3;
    float acc[8][8];
#pragma unroll
    for (int i = 0; i < 8; ++i)
#pragma unroll
        for (int j = 0; j < 8; ++j) acc[i][j] = 0.f;

    for (int k0 = 0; k0 < HID; k0 += 16) {
#pragma unroll
        for (int ld = 0; ld < 2; ++ld) {
            int idx = tid + ld * 256;
            int r  = idx >> 2;
            int kq = (idx & 3) << 2;
            int grow = row0 + r;
            float4 v = make_float4(0.f, 0.f, 0.f, 0.f);
            if (grow < NN) v = *(const float4*)&a_in[(size_t)grow * HID + k0 + kq];
            if (RELU) {
                v.x = fmaxf(v.x, 0.f); v.y = fmaxf(v.y, 0.f);
                v.z = fmaxf(v.z, 0.f); v.w = fmaxf(v.w, 0.f);
            }
            As[kq + 0][r] = v.x;
            As[kq + 1][r] = v.y;
            As[kq + 2][r] = v.z;
            As[kq + 3][r] = v.w;
            int kk = idx >> 5;
            int jq = (idx & 31) << 2;
            *(float4*)&Bs[kk][jq] = *(const float4*)&w[(size_t)(k0 + kk) * NOUT + n0 + jq];
        }
        __syncthreads();
#pragma unroll
        for (int kk = 0; kk < 16; ++kk) {
            float a[8], b[8];
            *(float4*)&a[0] = *(const float4*)&As[kk][tr];
            *(float4*)&a[4] = *(const float4*)&As[kk][tr + 4];
            *(float4*)&b[0] = *(const float4*)&Bs[kk][tc];
            *(float4*)&b[4] = *(const float4*)&Bs[kk][tc + 4];
#pragma unroll
            for (int i = 0; i < 8; ++i)
#pragma unroll
                for (int j = 0; j < 8; ++j) acc[i][j] += a[i] * b[j];
        }
        __syncthreads();
    }

    if (blockIdx.y == 0) {
#pragma unroll
        for (int i = 0; i < 8; ++i) {
            int grow = row0 + tr + i;
            if (grow >= NN) break;
#pragma unroll
            for (int j = 0; j < 8; ++j)
                hn[(size_t)grow * HID + tc + j] = acc[i][j] + bias[tc + j];
        }
    } else {
        int cbase = (blockIdx.y - 1) * 128;
#pragma unroll
        for (int i = 0; i < 8; ++i) {
            int grow = row0 + tr + i;
            if (grow >= NN) break;
#pragma unroll
            for (int j = 0; j < 8; ++j)
                xwb[(size_t)grow * (RELS * HID) + cbase + tc + j] = __float2bfloat16(acc[i][j]);
        }
    }
}

// ---------------- aggregate (atomic-free): one wave per dst node
// hn[dst][f] += sum_edges xwb[src][r*128+f] * escale
__global__ __launch_bounds__(256) void aggregate_kernel(const int* __restrict__ rowptr,
                                                        const int* __restrict__ epk,
                                                        const float* __restrict__ escale,
                                                        const __hip_bfloat16* __restrict__ xwb,
                                                        float* __restrict__ hn) {
    int node = (blockIdx.x << 2) + (threadIdx.x >> 6);
    if (node >= NN) return;
    int lane = threadIdx.x & 63;
    int beg = rowptr[node], end = rowptr[node + 1];
    float ax = 0.f, ay = 0.f;
    const unsigned short* xb = (const unsigned short*)xwb;
    for (int k = beg; k < end; ++k) {
        int p = epk[k];
        float s = escale[k];
        int src = p & 0xFFFFF;
        int r = p >> 20;
        ushort2 u = *(const ushort2*)(xb + (size_t)src * (RELS * HID) + r * HID + lane * 2);
        ax += bf2f(u.x) * s;
        ay += bf2f(u.y) * s;
    }
    float2* hp = (float2*)(hn + (size_t)node * HID) + lane;
    float2 c = *hp;
    c.x += ax; c.y += ay;
    *hp = c;
}

// ---------------- global mean pool (relu on load)
__global__ __launch_bounds__(256) void pool_kernel(const float* __restrict__ h,
                                                   const int* __restrict__ batch,
                                                   float* __restrict__ psum,
                                                   float* __restrict__ pcnt) {
    __shared__ float ls[GRAPHS * HID];
    __shared__ float lc[GRAPHS];
    int tid = threadIdx.x;
    for (int i = tid; i < GRAPHS * HID; i += 256) ls[i] = 0.f;
    if (tid < GRAPHS) lc[tid] = 0.f;
    __syncthreads();
    int base = blockIdx.x * 512;
    int f = tid & 127;
    int sub = tid >> 7;
    for (int it = 0; it < 256; ++it) {
        int node = base + it * 2 + sub;
        if (node < NN) {
            int g = batch[node];
            atomicAdd(&ls[g * HID + f], fmaxf(h[(size_t)node * HID + f], 0.f));
            if (f == 0) atomicAdd(&lc[g], 1.0f);
        }
    }
    __syncthreads();
    for (int i = tid; i < GRAPHS * HID; i += 256) atomicAdd(&psum[i], ls[i]);
    if (tid < GRAPHS) atomicAdd(&pcnt[tid], lc[tid]);
}

// ---------------- head
__global__ void head_kernel(const float* __restrict__ psum, const float* __restrict__ pcnt,
                            const float* __restrict__ g2, const float* __restrict__ b2,
                            const float* __restrict__ m2, const float* __restrict__ v2,
                            const float* __restrict__ fc1w, const float* __restrict__ fc1b,
                            const float* __restrict__ fc2w, const float* __restrict__ fc2b,
                            float* __restrict__ out) {
    __shared__ float v[HID];
    __shared__ float u[HID];
    __shared__ float lg[CLASSES];
    int j = threadIdx.x;
    float acc = 0.f;
    for (int g = 0; g < GRAPHS; ++g) {
        float val = psum[g * HID + j] / fmaxf(pcnt[g], 1.0f);
        val = (val - m2[j]) * rsqrtf(v2[j] + EPSV) * g2[j] + b2[j];
        acc += val;
    }
    v[j] = fmaxf(acc / (float)GRAPHS, 0.f);
    __syncthreads();
    float s = fc1b[j];
    for (int k = 0; k < HID; ++k) s += v[k] * fc1w[k * HID + j];
    u[j] = fmaxf(s, 0.f);
    __syncthreads();
    if (j < CLASSES) {
        float t = fc2b[j];
        for (int k = 0; k < HID; ++k) t += u[k] * fc2w[k * CLASSES + j];
        lg[j] = t;
    }
    __syncthreads();
    if (j < CLASSES) {
        float mx = lg[0];
        for (int c = 1; c < CLASSES; ++c) mx = fmaxf(mx, lg[c]);
        float se = 0.f;
        for (int c = 0; c < CLASSES; ++c) se += expf(lg[c] - mx);
        out[j] = lg[j] - mx - logf(se);
    }
}

extern "C" void kernel_launch(void* const* d_in, const int* in_sizes, int n_in,
                              void* d_out, int out_size, void* d_ws, size_t ws_size,
                              hipStream_t stream) {
    const float* x     = (const float*)d_in[0];
    const int*   ei    = (const int*)d_in[1];
    const int*   ea    = (const int*)d_in[2];
    const int*   batch = (const int*)d_in[3];
    const float* bn1g  = (const float*)d_in[4];
    const float* bn1b  = (const float*)d_in[5];
    const float* bn1m  = (const float*)d_in[6];
    const float* bn1v  = (const float*)d_in[7];
    const float* basis = (const float*)d_in[8];
    const float* comp  = (const float*)d_in[9];
    const float* root  = (const float*)d_in[10];
    const float* bias  = (const float*)d_in[11];
    const float* bn2g  = (const float*)d_in[12];
    const float* bn2b  = (const float*)d_in[13];
    const float* bn2m  = (const float*)d_in[14];
    const float* bn2v  = (const float*)d_in[15];
    const float* fc1w  = (const float*)d_in[16];
    const float* fc1b  = (const float*)d_in[17];
    const float* fc2w  = (const float*)d_in[18];
    const float* fc2b  = (const float*)d_in[19];

    float* ws = (float*)d_ws;
    size_t off = 0;
    float* wcat   = ws + off; off += (size_t)LAYERS * HID * NOUT;   // 442368
    float* h0     = ws + off; off += (size_t)NN * HID;              // 6.4M
    float* h1     = ws + off; off += (size_t)NN * HID;              // 6.4M
    float* deg    = ws + off; off += (size_t)NN * RELS;             // 400k (counts -> invdeg)
    float* psum   = ws + off; off += (size_t)GRAPHS * HID + GRAPHS;
    float* pcnt   = psum + GRAPHS * HID;
    float* escale = ws + off; off += (size_t)NE;                    // 500k
    int* degi     = (int*)(ws + off); off += (size_t)NN;
    int* rowptr   = (int*)(ws + off); off += (size_t)NN + 1;
    int* fillcnt  = (int*)(ws + off); off += (size_t)NN;
    int* bsum     = (int*)(ws + off); off += (size_t)SCAN_NBLK;
    int* epk      = (int*)(ws + off); off += (size_t)NE;            // 500k
    __hip_bfloat16* xwb = (__hip_bfloat16*)(ws + off);
    off += (size_t)NN * RELS * HID / 2;                             // 102.4MB as bf16
    if (ws_size < off * sizeof(float)) return;

    hipMemsetAsync(psum, 0, (GRAPHS * HID + GRAPHS) * sizeof(float), stream);
    hipMemsetAsync(deg, 0, (size_t)NN * RELS * sizeof(float), stream);
    hipMemsetAsync(fillcnt, 0, (size_t)NN * sizeof(int), stream);

    build_wcat<<<(LAYERS * HID * NOUT + 255) / 256, 256, 0, stream>>>(basis, comp, root, wcat);
    bn1_kernel<<<(NN * HID + 255) / 256, 256, 0, stream>>>(x, bn1g, bn1b, bn1m, bn1v, h0);

    // CSR build (once per call)
    deg_kernel<<<(NE + 255) / 256, 256, 0, stream>>>(ei, ea, deg);
    degi_kernel<<<(NN + 255) / 256, 256, 0, stream>>>(deg, degi);
    invdeg_kernel<<<(NN * RELS + 255) / 256, 256, 0, stream>>>(deg);
    scan_partial<<<SCAN_NBLK, 256, 0, stream>>>(degi, rowptr, bsum);
    scan_bsum<<<1, 64, 0, stream>>>(bsum);
    scan_add<<<(NN + 255) / 256, 256, 0, stream>>>(rowptr, bsum);
    fill_kernel<<<(NE + 255) / 256, 256, 0, stream>>>(ei, ea, rowptr, deg, fillcnt, epk, escale);

    dim3 ggrid((NN + 127) / 128, (RELS + 1));
    float* hin = h0;
    float* hout = h1;
    for (int l = 0; l < LAYERS; ++l) {
        const float* wl = wcat + (size_t)l * HID * NOUT;
        const float* bl = bias + (size_t)l * HID;
        if (l == 0)
            gemm_xw<false><<<ggrid, 256, 0, stream>>>(hin, wl, bl, hout, xwb);
        else
            gemm_xw<true><<<ggrid, 256, 0, stream>>>(hin, wl, bl, hout, xwb);
        aggregate_kernel<<<(NN + 3) / 4, 256, 0, stream>>>(rowptr, epk, escale, xwb, hout);
        float* t = hin; hin = hout; hout = t;
    }

    pool_kernel<<<(NN + 511) / 512, 256, 0, stream>>>(hin, batch, psum, pcnt);
    head_kernel<<<1, 128, 0, stream>>>(psum, pcnt, bn2g, bn2b, bn2m, bn2v,
                                       fc1w, fc1b, fc2w, fc2b, (float*)d_out);
}

// Round 4
// 677.866 us; speedup vs baseline: 5.4783x; 1.4931x over previous
//
#include <hip/hip_runtime.h>
#include <hip/hip_bf16.h>

#define NN 50000
#define NE 500000
#define HID 128
#define LAYERS 3
#define RELS 8
#define BASES 30
#define GRAPHS 16
#define CLASSES 8
#define EPSV 1e-5f
#define NOUT (HID * (RELS + 1))   // 1152
#define SCAN_CHUNK 1024
#define SCAN_NBLK ((NN + SCAN_CHUNK - 1) / SCAN_CHUNK)   // 49

typedef __attribute__((ext_vector_type(8))) short short8;   // 8 bf16 (4 VGPRs)
typedef __attribute__((ext_vector_type(4))) float f32x4;    // MFMA accumulator

__device__ __forceinline__ float bf2f(unsigned short u) {
    union { unsigned int i; float f; } x; x.i = ((unsigned int)u) << 16; return x.f;
}
__device__ __forceinline__ unsigned short f2bf(float f) {
    __hip_bfloat16 b = __float2bfloat16(f);
    return *(unsigned short*)&b;
}

// ---------------- wT: [L][1152 n][128 k] bf16;  wT[l][n][k] = B[k][n]
// n<128: root[l][k][n];  n=c*128+j (c=1+r): sum_b comp[l][r][b]*basis[l][b][k][j]
__global__ void build_wcat(const float* __restrict__ basis, const float* __restrict__ comp,
                           const float* __restrict__ root, unsigned short* __restrict__ wT) {
    int idx = blockIdx.x * blockDim.x + threadIdx.x;
    if (idx >= LAYERS * NOUT * HID) return;
    int k = idx & (HID - 1);
    int rest = idx >> 7;
    int n = rest % NOUT;
    int l = rest / NOUT;
    float v;
    if (n < HID) {
        v = root[((size_t)l * HID + k) * HID + n];
    } else {
        int r = (n >> 7) - 1;
        int j = n & (HID - 1);
        const float* cp = comp + ((size_t)l * RELS + r) * BASES;
        float s = 0.f;
        for (int b = 0; b < BASES; ++b)
            s += cp[b] * basis[(((size_t)(l * BASES + b)) * HID + k) * HID + j];
        v = s;
    }
    wT[idx] = f2bf(v);
}

// ---------------- BN1 (eval mode) -> bf16
__global__ void bn1_kernel(const float* __restrict__ x, const float* __restrict__ gamma,
                           const float* __restrict__ beta, const float* __restrict__ mean,
                           const float* __restrict__ var, unsigned short* __restrict__ habf) {
    int idx = blockIdx.x * blockDim.x + threadIdx.x;
    if (idx >= NN * HID) return;
    int f = idx & (HID - 1);
    habf[idx] = f2bf((x[idx] - mean[f]) * rsqrtf(var[f] + EPSV) * gamma[f] + beta[f]);
}

// ---------------- degree count per (dst, rel)
__global__ void deg_kernel(const int* __restrict__ ei, const int* __restrict__ ea,
                           float* __restrict__ deg) {
    int e = blockIdx.x * blockDim.x + threadIdx.x;
    if (e >= NE) return;
    int dst = ei[NE + e];
    atomicAdd(&deg[(size_t)dst * RELS + ea[e]], 1.0f);
}

__global__ void degi_kernel(const float* __restrict__ deg, int* __restrict__ degi) {
    int n = blockIdx.x * blockDim.x + threadIdx.x;
    if (n >= NN) return;
    float s = 0.f;
#pragma unroll
    for (int r = 0; r < RELS; ++r) s += deg[(size_t)n * RELS + r];
    degi[n] = (int)(s + 0.5f);
}

__global__ void invdeg_kernel(float* __restrict__ deg) {
    int i = blockIdx.x * blockDim.x + threadIdx.x;
    if (i >= NN * RELS) return;
    deg[i] = 1.0f / fmaxf(deg[i], 1.0f);
}

// ---------------- exclusive scan of degi -> rowptr
__global__ __launch_bounds__(256) void scan_partial(const int* __restrict__ degi,
                                                    int* __restrict__ rowptr,
                                                    int* __restrict__ bsum) {
    __shared__ int ssc[256];
    int t = threadIdx.x;
    int base = blockIdx.x * SCAN_CHUNK + t * 4;
    int v[4];
#pragma unroll
    for (int j = 0; j < 4; ++j) v[j] = (base + j < NN) ? degi[base + j] : 0;
    int tsum = v[0] + v[1] + v[2] + v[3];
    ssc[t] = tsum;
    __syncthreads();
    for (int ofs = 1; ofs < 256; ofs <<= 1) {
        int add = (t >= ofs) ? ssc[t - ofs] : 0;
        __syncthreads();
        ssc[t] += add;
        __syncthreads();
    }
    int excl = ssc[t] - tsum;
    int e = 0;
#pragma unroll
    for (int j = 0; j < 4; ++j) {
        if (base + j < NN) rowptr[base + j] = excl + e;
        e += v[j];
    }
    if (t == 255) bsum[blockIdx.x] = ssc[255];
}

__global__ void scan_bsum(int* __restrict__ bsum) {
    if (threadIdx.x == 0) {
        int acc = 0;
        for (int b = 0; b < SCAN_NBLK; ++b) { int v = bsum[b]; bsum[b] = acc; acc += v; }
    }
}

__global__ __launch_bounds__(256) void scan_add(int* __restrict__ rowptr,
                                                const int* __restrict__ bsum) {
    int i = blockIdx.x * blockDim.x + threadIdx.x;
    if (i < NN) rowptr[i] += bsum[i >> 10];
    if (i == 0) rowptr[NN] = NE;
}

// ---------------- fill CSR
__global__ void fill_kernel(const int* __restrict__ ei, const int* __restrict__ ea,
                            const int* __restrict__ rowptr, const float* __restrict__ invdeg,
                            int* __restrict__ fillcnt, int* __restrict__ epk,
                            float* __restrict__ escale) {
    int e = blockIdx.x * blockDim.x + threadIdx.x;
    if (e >= NE) return;
    int src = ei[e];
    int dst = ei[NE + e];
    int r = ea[e];
    int pos = atomicAdd(&fillcnt[dst], 1);
    int slot = rowptr[dst] + pos;
    epk[slot] = src | (r << 20);
    escale[slot] = invdeg[(size_t)dst * RELS + r];
}

// ---------------- MFMA GEMM: habf[N,128] @ wT^T -> tile0: hn fp32(+bias); tiles1-8: xwb bf16
// 128x128 tile, BK=64, 256 thr = 4 waves, each wave 64x64 via 16x16x32 bf16 MFMA
__global__ __launch_bounds__(256) void gemm_mfma(const unsigned short* __restrict__ habf,
                                                 const unsigned short* __restrict__ wT,
                                                 const float* __restrict__ bias,
                                                 float* __restrict__ hn,
                                                 unsigned short* __restrict__ xwb) {
    __shared__ __align__(16) unsigned short As[128][72];   // +8 pad: 4-bank row skew
    __shared__ __align__(16) unsigned short Bs[128][72];
    int tid = threadIdx.x;
    int wave = tid >> 6, lane = tid & 63;
    int wm = (wave & 1) * 64, wn = (wave >> 1) * 64;
    int quad = lane >> 4, l16 = lane & 15;
    int row0 = blockIdx.x * 128;
    int n0 = blockIdx.y * 128;

    f32x4 acc[4][4];
#pragma unroll
    for (int i = 0; i < 4; ++i)
#pragma unroll
        for (int j = 0; j < 4; ++j) acc[i][j] = (f32x4){0.f, 0.f, 0.f, 0.f};

    int srow = tid >> 1;          // 0..127
    int shalf = (tid & 1) * 32;   // 0 / 32 (bf16 elems)
    for (int k0 = 0; k0 < HID; k0 += 64) {
        // stage A (128 rows x 64 k) and B (128 n x 64 k), uint4 = 8 bf16
        int grow = row0 + srow;
        const uint4* ga = (const uint4*)(habf + (size_t)grow * HID + k0 + shalf);
        const uint4* gb = (const uint4*)(wT + (size_t)(n0 + srow) * HID + k0 + shalf);
        uint4 z = {0u, 0u, 0u, 0u};
#pragma unroll
        for (int c = 0; c < 4; ++c) {
            *(uint4*)&As[srow][shalf + c * 8] = (grow < NN) ? ga[c] : z;
            *(uint4*)&Bs[srow][shalf + c * 8] = gb[c];
        }
        __syncthreads();
#pragma unroll
        for (int kc = 0; kc < 2; ++kc) {
            int ko = kc * 32 + quad * 8;
            short8 a[4], b[4];
#pragma unroll
            for (int i = 0; i < 4; ++i) {
                a[i] = *(const short8*)&As[wm + i * 16 + l16][ko];
                b[i] = *(const short8*)&Bs[wn + i * 16 + l16][ko];
            }
#pragma unroll
            for (int i = 0; i < 4; ++i)
#pragma unroll
                for (int j = 0; j < 4; ++j)
                    acc[i][j] = __builtin_amdgcn_mfma_f32_16x16x32_bf16(a[i], b[j], acc[i][j], 0, 0, 0);
        }
        __syncthreads();
    }

    // epilogue: C/D layout col=lane&15, row=quad*4+reg
    if (blockIdx.y == 0) {
#pragma unroll
        for (int i = 0; i < 4; ++i)
#pragma unroll
            for (int reg = 0; reg < 4; ++reg) {
                int grow = row0 + wm + i * 16 + quad * 4 + reg;
                if (grow >= NN) continue;
#pragma unroll
                for (int j = 0; j < 4; ++j) {
                    int col = wn + j * 16 + l16;
                    hn[(size_t)grow * HID + col] = acc[i][j][reg] + bias[col];
                }
            }
    } else {
        int cbase = (blockIdx.y - 1) * 128;
#pragma unroll
        for (int i = 0; i < 4; ++i)
#pragma unroll
            for (int reg = 0; reg < 4; ++reg) {
                int grow = row0 + wm + i * 16 + quad * 4 + reg;
                if (grow >= NN) continue;
#pragma unroll
                for (int j = 0; j < 4; ++j) {
                    int col = wn + j * 16 + l16;
                    xwb[(size_t)grow * (RELS * HID) + cbase + col] = f2bf(acc[i][j][reg]);
                }
            }
    }
}

// ---------------- aggregate (atomic-free): one wave per dst node
// habf[dst] = bf16(relu(hn[dst] + sum_edges xwb[src][r*128+:]*escale))
__global__ __launch_bounds__(256) void aggregate_kernel(const int* __restrict__ rowptr,
                                                        const int* __restrict__ epk,
                                                        const float* __restrict__ escale,
                                                        const unsigned short* __restrict__ xwb,
                                                        const float* __restrict__ hn,
                                                        unsigned short* __restrict__ habf) {
    int node = (blockIdx.x << 2) + (threadIdx.x >> 6);
    if (node >= NN) return;
    int lane = threadIdx.x & 63;
    int beg = rowptr[node], end = rowptr[node + 1];
    float ax = 0.f, ay = 0.f;
    for (int k = beg; k < end; ++k) {
        int p = epk[k];
        float s = escale[k];
        int src = p & 0xFFFFF;
        int r = p >> 20;
        ushort2 u = *(const ushort2*)(xwb + (size_t)src * (RELS * HID) + r * HID + lane * 2);
        ax += bf2f(u.x) * s;
        ay += bf2f(u.y) * s;
    }
    const float2 c = *((const float2*)(hn + (size_t)node * HID) + lane);
    ushort2 o;
    o.x = f2bf(fmaxf(c.x + ax, 0.f));
    o.y = f2bf(fmaxf(c.y + ay, 0.f));
    *((ushort2*)(habf + (size_t)node * HID) + lane) = o;
}

// ---------------- global mean pool (reads bf16, already relu'd)
__global__ __launch_bounds__(256) void pool_kernel(const unsigned short* __restrict__ habf,
                                                   const int* __restrict__ batch,
                                                   float* __restrict__ psum,
                                                   float* __restrict__ pcnt) {
    __shared__ float ls[GRAPHS * HID];
    __shared__ float lc[GRAPHS];
    int tid = threadIdx.x;
    for (int i = tid; i < GRAPHS * HID; i += 256) ls[i] = 0.f;
    if (tid < GRAPHS) lc[tid] = 0.f;
    __syncthreads();
    int base = blockIdx.x * 512;
    int f = tid & 127;
    int sub = tid >> 7;
    for (int it = 0; it < 256; ++it) {
        int node = base + it * 2 + sub;
        if (node < NN) {
            int g = batch[node];
            atomicAdd(&ls[g * HID + f], bf2f(habf[(size_t)node * HID + f]));
            if (f == 0) atomicAdd(&lc[g], 1.0f);
        }
    }
    __syncthreads();
    for (int i = tid; i < GRAPHS * HID; i += 256) atomicAdd(&psum[i], ls[i]);
    if (tid < GRAPHS) atomicAdd(&pcnt[tid], lc[tid]);
}

// ---------------- head
__global__ void head_kernel(const float* __restrict__ psum, const float* __restrict__ pcnt,
                            const float* __restrict__ g2, const float* __restrict__ b2,
                            const float* __restrict__ m2, const float* __restrict__ v2,
                            const float* __restrict__ fc1w, const float* __restrict__ fc1b,
                            const float* __restrict__ fc2w, const float* __restrict__ fc2b,
                            float* __restrict__ out) {
    __shared__ float v[HID];
    __shared__ float u[HID];
    __shared__ float lg[CLASSES];
    int j = threadIdx.x;
    float acc = 0.f;
    for (int g = 0; g < GRAPHS; ++g) {
        float val = psum[g * HID + j] / fmaxf(pcnt[g], 1.0f);
        val = (val - m2[j]) * rsqrtf(v2[j] + EPSV) * g2[j] + b2[j];
        acc += val;
    }
    v[j] = fmaxf(acc / (float)GRAPHS, 0.f);
    __syncthreads();
    float s = fc1b[j];
    for (int k = 0; k < HID; ++k) s += v[k] * fc1w[k * HID + j];
    u[j] = fmaxf(s, 0.f);
    __syncthreads();
    if (j < CLASSES) {
        float t = fc2b[j];
        for (int k = 0; k < HID; ++k) t += u[k] * fc2w[k * CLASSES + j];
        lg[j] = t;
    }
    __syncthreads();
    if (j < CLASSES) {
        float mx = lg[0];
        for (int c = 1; c < CLASSES; ++c) mx = fmaxf(mx, lg[c]);
        float se = 0.f;
        for (int c = 0; c < CLASSES; ++c) se += expf(lg[c] - mx);
        out[j] = lg[j] - mx - logf(se);
    }
}

extern "C" void kernel_launch(void* const* d_in, const int* in_sizes, int n_in,
                              void* d_out, int out_size, void* d_ws, size_t ws_size,
                              hipStream_t stream) {
    const float* x     = (const float*)d_in[0];
    const int*   ei    = (const int*)d_in[1];
    const int*   ea    = (const int*)d_in[2];
    const int*   batch = (const int*)d_in[3];
    const float* bn1g  = (const float*)d_in[4];
    const float* bn1b  = (const float*)d_in[5];
    const float* bn1m  = (const float*)d_in[6];
    const float* bn1v  = (const float*)d_in[7];
    const float* basis = (const float*)d_in[8];
    const float* comp  = (const float*)d_in[9];
    const float* root  = (const float*)d_in[10];
    const float* bias  = (const float*)d_in[11];
    const float* bn2g  = (const float*)d_in[12];
    const float* bn2b  = (const float*)d_in[13];
    const float* bn2m  = (const float*)d_in[14];
    const float* bn2v  = (const float*)d_in[15];
    const float* fc1w  = (const float*)d_in[16];
    const float* fc1b  = (const float*)d_in[17];
    const float* fc2w  = (const float*)d_in[18];
    const float* fc2b  = (const float*)d_in[19];

    float* ws = (float*)d_ws;
    size_t off = 0;
    unsigned short* wT = (unsigned short*)(ws + off); off += (size_t)LAYERS * NOUT * HID / 2;
    float* hn     = ws + off; off += (size_t)NN * HID;
    unsigned short* habf = (unsigned short*)(ws + off); off += (size_t)NN * HID / 2;
    float* deg    = ws + off; off += (size_t)NN * RELS;
    float* psum   = ws + off; off += (size_t)GRAPHS * HID + GRAPHS;
    float* pcnt   = psum + GRAPHS * HID;
    float* escale = ws + off; off += (size_t)NE;
    int* degi     = (int*)(ws + off); off += (size_t)NN;
    int* rowptr   = (int*)(ws + off); off += (size_t)NN + 1;
    int* fillcnt  = (int*)(ws + off); off += (size_t)NN;
    int* bsum     = (int*)(ws + off); off += (size_t)SCAN_NBLK;
    int* epk      = (int*)(ws + off); off += (size_t)NE;
    off = (off + 3) & ~(size_t)3;                       // 16B-align xwb
    unsigned short* xwb = (unsigned short*)(ws + off);
    off += (size_t)NN * RELS * HID / 2;
    if (ws_size < off * sizeof(float)) return;

    hipMemsetAsync(psum, 0, (GRAPHS * HID + GRAPHS) * sizeof(float), stream);
    hipMemsetAsync(deg, 0, (size_t)NN * RELS * sizeof(float), stream);
    hipMemsetAsync(fillcnt, 0, (size_t)NN * sizeof(int), stream);

    build_wcat<<<(LAYERS * NOUT * HID + 255) / 256, 256, 0, stream>>>(basis, comp, root, wT);
    bn1_kernel<<<(NN * HID + 255) / 256, 256, 0, stream>>>(x, bn1g, bn1b, bn1m, bn1v, habf);

    // CSR build (once per call)
    deg_kernel<<<(NE + 255) / 256, 256, 0, stream>>>(ei, ea, deg);
    degi_kernel<<<(NN + 255) / 256, 256, 0, stream>>>(deg, degi);
    invdeg_kernel<<<(NN * RELS + 255) / 256, 256, 0, stream>>>(deg);
    scan_partial<<<SCAN_NBLK, 256, 0, stream>>>(degi, rowptr, bsum);
    scan_bsum<<<1, 64, 0, stream>>>(bsum);
    scan_add<<<(NN + 255) / 256, 256, 0, stream>>>(rowptr, bsum);
    fill_kernel<<<(NE + 255) / 256, 256, 0, stream>>>(ei, ea, rowptr, deg, fillcnt, epk, escale);

    dim3 ggrid((NN + 127) / 128, RELS + 1);
    for (int l = 0; l < LAYERS; ++l) {
        gemm_mfma<<<ggrid, 256, 0, stream>>>(habf, wT + (size_t)l * NOUT * HID,
                                             bias + (size_t)l * HID, hn, xwb);
        aggregate_kernel<<<(NN + 3) / 4, 256, 0, stream>>>(rowptr, epk, escale, xwb, hn, habf);
    }

    pool_kernel<<<(NN + 511) / 512, 256, 0, stream>>>(habf, batch, psum, pcnt);
    head_kernel<<<1, 128, 0, stream>>>(psum, pcnt, bn2g, bn2b, bn2m, bn2v,
                                       fc1w, fc1b, fc2w, fc2b, (float*)d_out);
}

// Round 5
// 553.410 us; speedup vs baseline: 6.7103x; 1.2249x over previous
//
#include <hip/hip_runtime.h>
#include <hip/hip_bf16.h>

#define NN 50000
#define NE 500000
#define HID 128
#define LAYERS 3
#define RELS 8
#define BASES 30
#define GRAPHS 16
#define CLASSES 8
#define EPSV 1e-5f
#define NOUT (HID * (RELS + 1))   // 1152
#define SCAN_CHUNK 1024
#define SCAN_NBLK ((NN + SCAN_CHUNK - 1) / SCAN_CHUNK)   // 49
#define PCHUNK 128

typedef __attribute__((ext_vector_type(8))) short short8;   // 8 bf16 (4 VGPRs)
typedef __attribute__((ext_vector_type(4))) float f32x4;    // MFMA accumulator

__device__ __forceinline__ float bf2f(unsigned short u) {
    union { unsigned int i; float f; } x; x.i = ((unsigned int)u) << 16; return x.f;
}
__device__ __forceinline__ unsigned short f2bf(float f) {
    __hip_bfloat16 b = __float2bfloat16(f);
    return *(unsigned short*)&b;
}

// ---------------- wT: [L][1152 n][128 k] bf16
__global__ void build_wcat(const float* __restrict__ basis, const float* __restrict__ comp,
                           const float* __restrict__ root, unsigned short* __restrict__ wT) {
    int idx = blockIdx.x * blockDim.x + threadIdx.x;
    if (idx >= LAYERS * NOUT * HID) return;
    int k = idx & (HID - 1);
    int rest = idx >> 7;
    int n = rest % NOUT;
    int l = rest / NOUT;
    float v;
    if (n < HID) {
        v = root[((size_t)l * HID + k) * HID + n];
    } else {
        int r = (n >> 7) - 1;
        int j = n & (HID - 1);
        const float* cp = comp + ((size_t)l * RELS + r) * BASES;
        float s = 0.f;
        for (int b = 0; b < BASES; ++b)
            s += cp[b] * basis[(((size_t)(l * BASES + b)) * HID + k) * HID + j];
        v = s;
    }
    wT[idx] = f2bf(v);
}

// ---------------- BN1 (eval mode) -> bf16
__global__ void bn1_kernel(const float* __restrict__ x, const float* __restrict__ gamma,
                           const float* __restrict__ beta, const float* __restrict__ mean,
                           const float* __restrict__ var, unsigned short* __restrict__ habf) {
    int idx = blockIdx.x * blockDim.x + threadIdx.x;
    if (idx >= NN * HID) return;
    int f = idx & (HID - 1);
    habf[idx] = f2bf((x[idx] - mean[f]) * rsqrtf(var[f] + EPSV) * gamma[f] + beta[f]);
}

// ---------------- degree count per (dst, rel)
__global__ void deg_kernel(const int* __restrict__ ei, const int* __restrict__ ea,
                           float* __restrict__ deg) {
    int e = blockIdx.x * blockDim.x + threadIdx.x;
    if (e >= NE) return;
    int dst = ei[NE + e];
    atomicAdd(&deg[(size_t)dst * RELS + ea[e]], 1.0f);
}

__global__ void degi_kernel(const float* __restrict__ deg, int* __restrict__ degi) {
    int n = blockIdx.x * blockDim.x + threadIdx.x;
    if (n >= NN) return;
    float s = 0.f;
#pragma unroll
    for (int r = 0; r < RELS; ++r) s += deg[(size_t)n * RELS + r];
    degi[n] = (int)(s + 0.5f);
}

__global__ void invdeg_kernel(float* __restrict__ deg) {
    int i = blockIdx.x * blockDim.x + threadIdx.x;
    if (i >= NN * RELS) return;
    deg[i] = 1.0f / fmaxf(deg[i], 1.0f);
}

// ---------------- exclusive scan of degi -> rowptr
__global__ __launch_bounds__(256) void scan_partial(const int* __restrict__ degi,
                                                    int* __restrict__ rowptr,
                                                    int* __restrict__ bsum) {
    __shared__ int ssc[256];
    int t = threadIdx.x;
    int base = blockIdx.x * SCAN_CHUNK + t * 4;
    int v[4];
#pragma unroll
    for (int j = 0; j < 4; ++j) v[j] = (base + j < NN) ? degi[base + j] : 0;
    int tsum = v[0] + v[1] + v[2] + v[3];
    ssc[t] = tsum;
    __syncthreads();
    for (int ofs = 1; ofs < 256; ofs <<= 1) {
        int add = (t >= ofs) ? ssc[t - ofs] : 0;
        __syncthreads();
        ssc[t] += add;
        __syncthreads();
    }
    int excl = ssc[t] - tsum;
    int e = 0;
#pragma unroll
    for (int j = 0; j < 4; ++j) {
        if (base + j < NN) rowptr[base + j] = excl + e;
        e += v[j];
    }
    if (t == 255) bsum[blockIdx.x] = ssc[255];
}

__global__ void scan_bsum(int* __restrict__ bsum) {
    if (threadIdx.x == 0) {
        int acc = 0;
        for (int b = 0; b < SCAN_NBLK; ++b) { int v = bsum[b]; bsum[b] = acc; acc += v; }
    }
}

__global__ __launch_bounds__(256) void scan_add(int* __restrict__ rowptr,
                                                const int* __restrict__ bsum) {
    int i = blockIdx.x * blockDim.x + threadIdx.x;
    if (i < NN) rowptr[i] += bsum[i >> 10];
    if (i == 0) rowptr[NN] = NE;
}

// ---------------- fill CSR
__global__ void fill_kernel(const int* __restrict__ ei, const int* __restrict__ ea,
                            const int* __restrict__ rowptr, const float* __restrict__ invdeg,
                            int* __restrict__ fillcnt, int* __restrict__ epk,
                            float* __restrict__ escale) {
    int e = blockIdx.x * blockDim.x + threadIdx.x;
    if (e >= NE) return;
    int src = ei[e];
    int dst = ei[NE + e];
    int r = ea[e];
    int pos = atomicAdd(&fillcnt[dst], 1);
    int slot = rowptr[dst] + pos;
    epk[slot] = src | (r << 20);
    escale[slot] = invdeg[(size_t)dst * RELS + r];
}

// ---------------- MFMA GEMM: habf[N,128] @ wT^T -> tile0: hn fp32(+bias); tiles1-8: xwb bf16
__global__ __launch_bounds__(256) void gemm_mfma(const unsigned short* __restrict__ habf,
                                                 const unsigned short* __restrict__ wT,
                                                 const float* __restrict__ bias,
                                                 float* __restrict__ hn,
                                                 unsigned short* __restrict__ xwb) {
    __shared__ __align__(16) unsigned short As[128][72];
    __shared__ __align__(16) unsigned short Bs[128][72];
    int tid = threadIdx.x;
    int wave = tid >> 6, lane = tid & 63;
    int wm = (wave & 1) * 64, wn = (wave >> 1) * 64;
    int quad = lane >> 4, l16 = lane & 15;
    int row0 = blockIdx.x * 128;
    int n0 = blockIdx.y * 128;

    f32x4 acc[4][4];
#pragma unroll
    for (int i = 0; i < 4; ++i)
#pragma unroll
        for (int j = 0; j < 4; ++j) acc[i][j] = (f32x4){0.f, 0.f, 0.f, 0.f};

    int srow = tid >> 1;
    int shalf = (tid & 1) * 32;
    for (int k0 = 0; k0 < HID; k0 += 64) {
        int grow = row0 + srow;
        const uint4* ga = (const uint4*)(habf + (size_t)grow * HID + k0 + shalf);
        const uint4* gb = (const uint4*)(wT + (size_t)(n0 + srow) * HID + k0 + shalf);
        uint4 z = {0u, 0u, 0u, 0u};
#pragma unroll
        for (int c = 0; c < 4; ++c) {
            *(uint4*)&As[srow][shalf + c * 8] = (grow < NN) ? ga[c] : z;
            *(uint4*)&Bs[srow][shalf + c * 8] = gb[c];
        }
        __syncthreads();
#pragma unroll
        for (int kc = 0; kc < 2; ++kc) {
            int ko = kc * 32 + quad * 8;
            short8 a[4], b[4];
#pragma unroll
            for (int i = 0; i < 4; ++i) {
                a[i] = *(const short8*)&As[wm + i * 16 + l16][ko];
                b[i] = *(const short8*)&Bs[wn + i * 16 + l16][ko];
            }
#pragma unroll
            for (int i = 0; i < 4; ++i)
#pragma unroll
                for (int j = 0; j < 4; ++j)
                    acc[i][j] = __builtin_amdgcn_mfma_f32_16x16x32_bf16(a[i], b[j], acc[i][j], 0, 0, 0);
        }
        __syncthreads();
    }

    if (blockIdx.y == 0) {
#pragma unroll
        for (int i = 0; i < 4; ++i)
#pragma unroll
            for (int reg = 0; reg < 4; ++reg) {
                int grow = row0 + wm + i * 16 + quad * 4 + reg;
                if (grow >= NN) continue;
#pragma unroll
                for (int j = 0; j < 4; ++j) {
                    int col = wn + j * 16 + l16;
                    hn[(size_t)grow * HID + col] = acc[i][j][reg] + bias[col];
                }
            }
    } else {
        int cbase = (blockIdx.y - 1) * 128;
#pragma unroll
        for (int i = 0; i < 4; ++i)
#pragma unroll
            for (int reg = 0; reg < 4; ++reg) {
                int grow = row0 + wm + i * 16 + quad * 4 + reg;
                if (grow >= NN) continue;
#pragma unroll
                for (int j = 0; j < 4; ++j) {
                    int col = wn + j * 16 + l16;
                    xwb[(size_t)grow * (RELS * HID) + cbase + col] = f2bf(acc[i][j][reg]);
                }
            }
    }
}

// ---------------- aggregate (atomic-free): one wave per dst node, edge prefetch + shfl
__global__ __launch_bounds__(256) void aggregate_kernel(const int* __restrict__ rowptr,
                                                        const int* __restrict__ epk,
                                                        const float* __restrict__ escale,
                                                        const unsigned short* __restrict__ xwb,
                                                        const float* __restrict__ hn,
                                                        unsigned short* __restrict__ habf) {
    int node = (blockIdx.x << 2) + (threadIdx.x >> 6);
    if (node >= NN) return;
    int lane = threadIdx.x & 63;
    int beg = rowptr[node], end = rowptr[node + 1];
    float ax = 0.f, ay = 0.f;
    for (int b0 = beg; b0 < end; b0 += 64) {
        int cnt = min(64, end - b0);
        int myp = 0; float mys = 0.f;
        if (lane < cnt) { myp = epk[b0 + lane]; mys = escale[b0 + lane]; }
        int j = 0;
        for (; j + 4 <= cnt; j += 4) {
            int p0 = __shfl(myp, j),     p1 = __shfl(myp, j + 1);
            int p2 = __shfl(myp, j + 2), p3 = __shfl(myp, j + 3);
            float s0 = __shfl(mys, j),     s1 = __shfl(mys, j + 1);
            float s2 = __shfl(mys, j + 2), s3 = __shfl(mys, j + 3);
            ushort2 u0 = *(const ushort2*)(xwb + (size_t)(p0 & 0xFFFFF) * (RELS * HID) + (p0 >> 20) * HID + lane * 2);
            ushort2 u1 = *(const ushort2*)(xwb + (size_t)(p1 & 0xFFFFF) * (RELS * HID) + (p1 >> 20) * HID + lane * 2);
            ushort2 u2 = *(const ushort2*)(xwb + (size_t)(p2 & 0xFFFFF) * (RELS * HID) + (p2 >> 20) * HID + lane * 2);
            ushort2 u3 = *(const ushort2*)(xwb + (size_t)(p3 & 0xFFFFF) * (RELS * HID) + (p3 >> 20) * HID + lane * 2);
            ax += bf2f(u0.x) * s0 + bf2f(u1.x) * s1 + bf2f(u2.x) * s2 + bf2f(u3.x) * s3;
            ay += bf2f(u0.y) * s0 + bf2f(u1.y) * s1 + bf2f(u2.y) * s2 + bf2f(u3.y) * s3;
        }
        for (; j < cnt; ++j) {
            int p = __shfl(myp, j);
            float s = __shfl(mys, j);
            ushort2 u = *(const ushort2*)(xwb + (size_t)(p & 0xFFFFF) * (RELS * HID) + (p >> 20) * HID + lane * 2);
            ax += bf2f(u.x) * s;
            ay += bf2f(u.y) * s;
        }
    }
    const float2 c = *((const float2*)(hn + (size_t)node * HID) + lane);
    ushort2 o;
    o.x = f2bf(fmaxf(c.x + ax, 0.f));
    o.y = f2bf(fmaxf(c.y + ay, 0.f));
    *((ushort2*)(habf + (size_t)node * HID) + lane) = o;
}

// ---------------- global mean pool: sorted-batch register accumulation, flush on g-change
__global__ __launch_bounds__(256) void pool_kernel(const unsigned short* __restrict__ habf,
                                                   const int* __restrict__ batch,
                                                   float* __restrict__ psum,
                                                   float* __restrict__ pcnt) {
    int tid = threadIdx.x;
    int f = tid & 127;
    int sub = tid >> 7;                 // 0/1: two nodes in flight per block
    int base = blockIdx.x * PCHUNK;
    float acc = 0.f, cnt = 0.f;
    int gcur = -1;
    for (int it = 0; it < PCHUNK / 2; ++it) {
        int node = base + it * 2 + sub;
        if (node >= NN) break;
        int g = batch[node];
        if (g != gcur) {
            if (gcur >= 0) {
                atomicAdd(&psum[gcur * HID + f], acc);
                if (f == 0) atomicAdd(&pcnt[gcur], cnt);
            }
            gcur = g; acc = 0.f; cnt = 0.f;
        }
        acc += bf2f(habf[(size_t)node * HID + f]);
        cnt += 1.f;
    }
    if (gcur >= 0) {
        atomicAdd(&psum[gcur * HID + f], acc);
        if (f == 0) atomicAdd(&pcnt[gcur], cnt);
    }
}

// ---------------- head
__global__ void head_kernel(const float* __restrict__ psum, const float* __restrict__ pcnt,
                            const float* __restrict__ g2, const float* __restrict__ b2,
                            const float* __restrict__ m2, const float* __restrict__ v2,
                            const float* __restrict__ fc1w, const float* __restrict__ fc1b,
                            const float* __restrict__ fc2w, const float* __restrict__ fc2b,
                            float* __restrict__ out) {
    __shared__ float v[HID];
    __shared__ float u[HID];
    __shared__ float lg[CLASSES];
    int j = threadIdx.x;
    float acc = 0.f;
    for (int g = 0; g < GRAPHS; ++g) {
        float val = psum[g * HID + j] / fmaxf(pcnt[g], 1.0f);
        val = (val - m2[j]) * rsqrtf(v2[j] + EPSV) * g2[j] + b2[j];
        acc += val;
    }
    v[j] = fmaxf(acc / (float)GRAPHS, 0.f);
    __syncthreads();
    float s = fc1b[j];
    for (int k = 0; k < HID; ++k) s += v[k] * fc1w[k * HID + j];
    u[j] = fmaxf(s, 0.f);
    __syncthreads();
    if (j < CLASSES) {
        float t = fc2b[j];
        for (int k = 0; k < HID; ++k) t += u[k] * fc2w[k * CLASSES + j];
        lg[j] = t;
    }
    __syncthreads();
    if (j < CLASSES) {
        float mx = lg[0];
        for (int c = 1; c < CLASSES; ++c) mx = fmaxf(mx, lg[c]);
        float se = 0.f;
        for (int c = 0; c < CLASSES; ++c) se += expf(lg[c] - mx);
        out[j] = lg[j] - mx - logf(se);
    }
}

extern "C" void kernel_launch(void* const* d_in, const int* in_sizes, int n_in,
                              void* d_out, int out_size, void* d_ws, size_t ws_size,
                              hipStream_t stream) {
    const float* x     = (const float*)d_in[0];
    const int*   ei    = (const int*)d_in[1];
    const int*   ea    = (const int*)d_in[2];
    const int*   batch = (const int*)d_in[3];
    const float* bn1g  = (const float*)d_in[4];
    const float* bn1b  = (const float*)d_in[5];
    const float* bn1m  = (const float*)d_in[6];
    const float* bn1v  = (const float*)d_in[7];
    const float* basis = (const float*)d_in[8];
    const float* comp  = (const float*)d_in[9];
    const float* root  = (const float*)d_in[10];
    const float* bias  = (const float*)d_in[11];
    const float* bn2g  = (const float*)d_in[12];
    const float* bn2b  = (const float*)d_in[13];
    const float* bn2m  = (const float*)d_in[14];
    const float* bn2v  = (const float*)d_in[15];
    const float* fc1w  = (const float*)d_in[16];
    const float* fc1b  = (const float*)d_in[17];
    const float* fc2w  = (const float*)d_in[18];
    const float* fc2b  = (const float*)d_in[19];

    float* ws = (float*)d_ws;
    size_t off = 0;
    unsigned short* wT = (unsigned short*)(ws + off); off += (size_t)LAYERS * NOUT * HID / 2;
    float* hn     = ws + off; off += (size_t)NN * HID;
    unsigned short* habf = (unsigned short*)(ws + off); off += (size_t)NN * HID / 2;
    float* deg    = ws + off; off += (size_t)NN * RELS;
    float* psum   = ws + off; off += (size_t)GRAPHS * HID + GRAPHS;
    float* pcnt   = psum + GRAPHS * HID;
    float* escale = ws + off; off += (size_t)NE;
    int* degi     = (int*)(ws + off); off += (size_t)NN;
    int* rowptr   = (int*)(ws + off); off += (size_t)NN + 1;
    int* fillcnt  = (int*)(ws + off); off += (size_t)NN;
    int* bsum     = (int*)(ws + off); off += (size_t)SCAN_NBLK;
    int* epk      = (int*)(ws + off); off += (size_t)NE;
    off = (off + 3) & ~(size_t)3;
    unsigned short* xwb = (unsigned short*)(ws + off);
    off += (size_t)NN * RELS * HID / 2;
    if (ws_size < off * sizeof(float)) return;

    hipMemsetAsync(psum, 0, (GRAPHS * HID + GRAPHS) * sizeof(float), stream);
    hipMemsetAsync(deg, 0, (size_t)NN * RELS * sizeof(float), stream);
    hipMemsetAsync(fillcnt, 0, (size_t)NN * sizeof(int), stream);

    build_wcat<<<(LAYERS * NOUT * HID + 255) / 256, 256, 0, stream>>>(basis, comp, root, wT);
    bn1_kernel<<<(NN * HID + 255) / 256, 256, 0, stream>>>(x, bn1g, bn1b, bn1m, bn1v, habf);

    deg_kernel<<<(NE + 255) / 256, 256, 0, stream>>>(ei, ea, deg);
    degi_kernel<<<(NN + 255) / 256, 256, 0, stream>>>(deg, degi);
    invdeg_kernel<<<(NN * RELS + 255) / 256, 256, 0, stream>>>(deg);
    scan_partial<<<SCAN_NBLK, 256, 0, stream>>>(degi, rowptr, bsum);
    scan_bsum<<<1, 64, 0, stream>>>(bsum);
    scan_add<<<(NN + 255) / 256, 256, 0, stream>>>(rowptr, bsum);
    fill_kernel<<<(NE + 255) / 256, 256, 0, stream>>>(ei, ea, rowptr, deg, fillcnt, epk, escale);

    dim3 ggrid((NN + 127) / 128, RELS + 1);
    for (int l = 0; l < LAYERS; ++l) {
        gemm_mfma<<<ggrid, 256, 0, stream>>>(habf, wT + (size_t)l * NOUT * HID,
                                             bias + (size_t)l * HID, hn, xwb);
        aggregate_kernel<<<(NN + 3) / 4, 256, 0, stream>>>(rowptr, epk, escale, xwb, hn, habf);
    }

    pool_kernel<<<(NN + PCHUNK - 1) / PCHUNK, 256, 0, stream>>>(habf, batch, psum, pcnt);
    head_kernel<<<1, 128, 0, stream>>>(psum, pcnt, bn2g, bn2b, bn2m, bn2v,
                                       fc1w, fc1b, fc2w, fc2b, (float*)d_out);
}

// Round 6
// 530.416 us; speedup vs baseline: 7.0012x; 1.0434x over previous
//
#include <hip/hip_runtime.h>
#include <hip/hip_bf16.h>

#define NN 50000
#define NE 500000
#define HID 128
#define LAYERS 3
#define RELS 8
#define BASES 30
#define GRAPHS 16
#define CLASSES 8
#define EPSV 1e-5f
#define NOUT (HID * (RELS + 1))   // 1152
#define SCAN_CHUNK 1024
#define SCAN_NBLK ((NN + SCAN_CHUNK - 1) / SCAN_CHUNK)   // 49
#define PCHUNK 128

typedef __attribute__((ext_vector_type(8))) short short8;   // 8 bf16 (4 VGPRs)
typedef __attribute__((ext_vector_type(4))) float f32x4;    // MFMA accumulator

__device__ __forceinline__ float bf2f(unsigned short u) {
    union { unsigned int i; float f; } x; x.i = ((unsigned int)u) << 16; return x.f;
}
__device__ __forceinline__ unsigned short f2bf(float f) {
    __hip_bfloat16 b = __float2bfloat16(f);
    return *(unsigned short*)&b;
}

// ---------------- wT: [L][1152 n][128 k] bf16
__global__ void build_wcat(const float* __restrict__ basis, const float* __restrict__ comp,
                           const float* __restrict__ root, unsigned short* __restrict__ wT) {
    int idx = blockIdx.x * blockDim.x + threadIdx.x;
    if (idx >= LAYERS * NOUT * HID) return;
    int k = idx & (HID - 1);
    int rest = idx >> 7;
    int n = rest % NOUT;
    int l = rest / NOUT;
    float v;
    if (n < HID) {
        v = root[((size_t)l * HID + k) * HID + n];
    } else {
        int r = (n >> 7) - 1;
        int j = n & (HID - 1);
        const float* cp = comp + ((size_t)l * RELS + r) * BASES;
        float s = 0.f;
        for (int b = 0; b < BASES; ++b)
            s += cp[b] * basis[(((size_t)(l * BASES + b)) * HID + k) * HID + j];
        v = s;
    }
    wT[idx] = f2bf(v);
}

// ---------------- BN1 (eval mode) -> bf16
__global__ void bn1_kernel(const float* __restrict__ x, const float* __restrict__ gamma,
                           const float* __restrict__ beta, const float* __restrict__ mean,
                           const float* __restrict__ var, unsigned short* __restrict__ habf) {
    int idx = blockIdx.x * blockDim.x + threadIdx.x;
    if (idx >= NN * HID) return;
    int f = idx & (HID - 1);
    habf[idx] = f2bf((x[idx] - mean[f]) * rsqrtf(var[f] + EPSV) * gamma[f] + beta[f]);
}

// ---------------- degree count per (dst, rel)
__global__ void deg_kernel(const int* __restrict__ ei, const int* __restrict__ ea,
                           float* __restrict__ deg) {
    int e = blockIdx.x * blockDim.x + threadIdx.x;
    if (e >= NE) return;
    int dst = ei[NE + e];
    atomicAdd(&deg[(size_t)dst * RELS + ea[e]], 1.0f);
}

// degi = int total degree; deg -> invdeg in-place
__global__ void invdeg_kernel(float* __restrict__ deg, int* __restrict__ degi) {
    int n = blockIdx.x * blockDim.x + threadIdx.x;
    if (n >= NN) return;
    float s = 0.f;
#pragma unroll
    for (int r = 0; r < RELS; ++r) {
        float d = deg[(size_t)n * RELS + r];
        s += d;
        deg[(size_t)n * RELS + r] = 1.0f / fmaxf(d, 1.0f);
    }
    degi[n] = (int)(s + 0.5f);
}

// ---------------- exclusive scan of degi -> rowptr
__global__ __launch_bounds__(256) void scan_partial(const int* __restrict__ degi,
                                                    int* __restrict__ rowptr,
                                                    int* __restrict__ bsum) {
    __shared__ int ssc[256];
    int t = threadIdx.x;
    int base = blockIdx.x * SCAN_CHUNK + t * 4;
    int v[4];
#pragma unroll
    for (int j = 0; j < 4; ++j) v[j] = (base + j < NN) ? degi[base + j] : 0;
    int tsum = v[0] + v[1] + v[2] + v[3];
    ssc[t] = tsum;
    __syncthreads();
    for (int ofs = 1; ofs < 256; ofs <<= 1) {
        int add = (t >= ofs) ? ssc[t - ofs] : 0;
        __syncthreads();
        ssc[t] += add;
        __syncthreads();
    }
    int excl = ssc[t] - tsum;
    int e = 0;
#pragma unroll
    for (int j = 0; j < 4; ++j) {
        if (base + j < NN) rowptr[base + j] = excl + e;
        e += v[j];
    }
    if (t == 255) bsum[blockIdx.x] = ssc[255];
}

__global__ void scan_bsum(int* __restrict__ bsum) {
    if (threadIdx.x == 0) {
        int acc = 0;
        for (int b = 0; b < SCAN_NBLK; ++b) { int v = bsum[b]; bsum[b] = acc; acc += v; }
    }
}

__global__ __launch_bounds__(256) void scan_add(int* __restrict__ rowptr,
                                                const int* __restrict__ bsum) {
    int i = blockIdx.x * blockDim.x + threadIdx.x;
    if (i < NN) rowptr[i] += bsum[i >> 10];
    if (i == 0) rowptr[NN] = NE;
}

// ---------------- fill CSR
__global__ void fill_kernel(const int* __restrict__ ei, const int* __restrict__ ea,
                            const int* __restrict__ rowptr, const float* __restrict__ invdeg,
                            int* __restrict__ fillcnt, int* __restrict__ epk,
                            float* __restrict__ escale) {
    int e = blockIdx.x * blockDim.x + threadIdx.x;
    if (e >= NE) return;
    int src = ei[e];
    int dst = ei[NE + e];
    int r = ea[e];
    int pos = atomicAdd(&fillcnt[dst], 1);
    int slot = rowptr[dst] + pos;
    epk[slot] = src | (r << 20);
    escale[slot] = invdeg[(size_t)dst * RELS + r];
}

// ---------------- MFMA GEMM, single-pass: one block = 64-row stripe, loops all 9 n-tiles.
// A staged once (64x128), B staged per (n-tile, k-half). tile0 -> hnb bf16(+bias); 1..8 -> xwb.
__global__ __launch_bounds__(256) void gemm_mfma(const unsigned short* __restrict__ habf,
                                                 const unsigned short* __restrict__ wT,
                                                 const float* __restrict__ bias,
                                                 unsigned short* __restrict__ hnb,
                                                 unsigned short* __restrict__ xwb) {
    __shared__ __align__(16) unsigned short As[64][136];   // 64 rows x 128 k (+8 pad)
    __shared__ __align__(16) unsigned short Bs[128][72];   // 128 n x 64 k (+8 pad)
    int tid = threadIdx.x;
    int wave = tid >> 6, lane = tid & 63;
    int wm = (wave & 1) * 32, wn = (wave >> 1) * 64;
    int quad = lane >> 4, l16 = lane & 15;
    int row0 = blockIdx.x * 64;

    // stage A once: 4 threads/row, each 4 uint4 (32 bf16)
    {
        int r = tid >> 2;
        int c0 = (tid & 3) * 32;
        int grow = row0 + r;
        const uint4* ga = (const uint4*)(habf + (size_t)grow * HID + c0);
        uint4 z = {0u, 0u, 0u, 0u};
#pragma unroll
        for (int c = 0; c < 4; ++c)
            *(uint4*)&As[r][c0 + c * 8] = (grow < NN) ? ga[c] : z;
    }

    for (int n0 = 0; n0 < RELS + 1; ++n0) {
        f32x4 acc[2][4];
#pragma unroll
        for (int i = 0; i < 2; ++i)
#pragma unroll
            for (int j = 0; j < 4; ++j) acc[i][j] = (f32x4){0.f, 0.f, 0.f, 0.f};

#pragma unroll
        for (int kh = 0; kh < 2; ++kh) {
            __syncthreads();   // Bs consumed (or A staged on first pass)
            {
                int r = tid >> 1;
                int c0 = (tid & 1) * 32;
                const uint4* gb = (const uint4*)(wT + (size_t)(n0 * 128 + r) * HID + kh * 64 + c0);
#pragma unroll
                for (int c = 0; c < 4; ++c)
                    *(uint4*)&Bs[r][c0 + c * 8] = gb[c];
            }
            __syncthreads();
#pragma unroll
            for (int kc = 0; kc < 2; ++kc) {
                int ko = kc * 32 + quad * 8;
                short8 a[2], b[4];
                a[0] = *(const short8*)&As[wm + l16][kh * 64 + ko];
                a[1] = *(const short8*)&As[wm + 16 + l16][kh * 64 + ko];
#pragma unroll
                for (int j = 0; j < 4; ++j)
                    b[j] = *(const short8*)&Bs[wn + j * 16 + l16][ko];
#pragma unroll
                for (int i = 0; i < 2; ++i)
#pragma unroll
                    for (int j = 0; j < 4; ++j)
                        acc[i][j] = __builtin_amdgcn_mfma_f32_16x16x32_bf16(a[i], b[j], acc[i][j], 0, 0, 0);
            }
        }

        // epilogue for this n-tile (C/D: col=lane&15, row=quad*4+reg)
        if (n0 == 0) {
#pragma unroll
            for (int i = 0; i < 2; ++i)
#pragma unroll
                for (int reg = 0; reg < 4; ++reg) {
                    int grow = row0 + wm + i * 16 + quad * 4 + reg;
                    if (grow >= NN) continue;
#pragma unroll
                    for (int j = 0; j < 4; ++j) {
                        int col = wn + j * 16 + l16;
                        hnb[(size_t)grow * HID + col] = f2bf(acc[i][j][reg] + bias[col]);
                    }
                }
        } else {
            int cbase = (n0 - 1) * 128;
#pragma unroll
            for (int i = 0; i < 2; ++i)
#pragma unroll
                for (int reg = 0; reg < 4; ++reg) {
                    int grow = row0 + wm + i * 16 + quad * 4 + reg;
                    if (grow >= NN) continue;
#pragma unroll
                    for (int j = 0; j < 4; ++j) {
                        int col = wn + j * 16 + l16;
                        xwb[(size_t)grow * (RELS * HID) + cbase + col] = f2bf(acc[i][j][reg]);
                    }
                }
        }
    }
}

// ---------------- aggregate (atomic-free): one wave per dst node, edge prefetch + shfl
__global__ __launch_bounds__(256) void aggregate_kernel(const int* __restrict__ rowptr,
                                                        const int* __restrict__ epk,
                                                        const float* __restrict__ escale,
                                                        const unsigned short* __restrict__ xwb,
                                                        const unsigned short* __restrict__ hnb,
                                                        unsigned short* __restrict__ habf) {
    int node = (blockIdx.x << 2) + (threadIdx.x >> 6);
    if (node >= NN) return;
    int lane = threadIdx.x & 63;
    int beg = rowptr[node], end = rowptr[node + 1];
    float ax = 0.f, ay = 0.f;
    for (int b0 = beg; b0 < end; b0 += 64) {
        int cnt = min(64, end - b0);
        int myp = 0; float mys = 0.f;
        if (lane < cnt) { myp = epk[b0 + lane]; mys = escale[b0 + lane]; }
        int j = 0;
        for (; j + 4 <= cnt; j += 4) {
            int p0 = __shfl(myp, j),     p1 = __shfl(myp, j + 1);
            int p2 = __shfl(myp, j + 2), p3 = __shfl(myp, j + 3);
            float s0 = __shfl(mys, j),     s1 = __shfl(mys, j + 1);
            float s2 = __shfl(mys, j + 2), s3 = __shfl(mys, j + 3);
            ushort2 u0 = *(const ushort2*)(xwb + (size_t)(p0 & 0xFFFFF) * (RELS * HID) + (p0 >> 20) * HID + lane * 2);
            ushort2 u1 = *(const ushort2*)(xwb + (size_t)(p1 & 0xFFFFF) * (RELS * HID) + (p1 >> 20) * HID + lane * 2);
            ushort2 u2 = *(const ushort2*)(xwb + (size_t)(p2 & 0xFFFFF) * (RELS * HID) + (p2 >> 20) * HID + lane * 2);
            ushort2 u3 = *(const ushort2*)(xwb + (size_t)(p3 & 0xFFFFF) * (RELS * HID) + (p3 >> 20) * HID + lane * 2);
            ax += bf2f(u0.x) * s0 + bf2f(u1.x) * s1 + bf2f(u2.x) * s2 + bf2f(u3.x) * s3;
            ay += bf2f(u0.y) * s0 + bf2f(u1.y) * s1 + bf2f(u2.y) * s2 + bf2f(u3.y) * s3;
        }
        for (; j < cnt; ++j) {
            int p = __shfl(myp, j);
            float s = __shfl(mys, j);
            ushort2 u = *(const ushort2*)(xwb + (size_t)(p & 0xFFFFF) * (RELS * HID) + (p >> 20) * HID + lane * 2);
            ax += bf2f(u.x) * s;
            ay += bf2f(u.y) * s;
        }
    }
    ushort2 cu = *((const ushort2*)(hnb + (size_t)node * HID) + lane);
    ushort2 o;
    o.x = f2bf(fmaxf(bf2f(cu.x) + ax, 0.f));
    o.y = f2bf(fmaxf(bf2f(cu.y) + ay, 0.f));
    *((ushort2*)(habf + (size_t)node * HID) + lane) = o;
}

// ---------------- global mean pool: sorted-batch register accumulation, flush on g-change
__global__ __launch_bounds__(256) void pool_kernel(const unsigned short* __restrict__ habf,
                                                   const int* __restrict__ batch,
                                                   float* __restrict__ psum,
                                                   float* __restrict__ pcnt) {
    int tid = threadIdx.x;
    int f = tid & 127;
    int sub = tid >> 7;
    int base = blockIdx.x * PCHUNK;
    float acc = 0.f, cnt = 0.f;
    int gcur = -1;
    for (int it = 0; it < PCHUNK / 2; ++it) {
        int node = base + it * 2 + sub;
        if (node >= NN) break;
        int g = batch[node];
        if (g != gcur) {
            if (gcur >= 0) {
                atomicAdd(&psum[gcur * HID + f], acc);
                if (f == 0) atomicAdd(&pcnt[gcur], cnt);
            }
            gcur = g; acc = 0.f; cnt = 0.f;
        }
        acc += bf2f(habf[(size_t)node * HID + f]);
        cnt += 1.f;
    }
    if (gcur >= 0) {
        atomicAdd(&psum[gcur * HID + f], acc);
        if (f == 0) atomicAdd(&pcnt[gcur], cnt);
    }
}

// ---------------- head
__global__ void head_kernel(const float* __restrict__ psum, const float* __restrict__ pcnt,
                            const float* __restrict__ g2, const float* __restrict__ b2,
                            const float* __restrict__ m2, const float* __restrict__ v2,
                            const float* __restrict__ fc1w, const float* __restrict__ fc1b,
                            const float* __restrict__ fc2w, const float* __restrict__ fc2b,
                            float* __restrict__ out) {
    __shared__ float v[HID];
    __shared__ float u[HID];
    __shared__ float lg[CLASSES];
    int j = threadIdx.x;
    float acc = 0.f;
    for (int g = 0; g < GRAPHS; ++g) {
        float val = psum[g * HID + j] / fmaxf(pcnt[g], 1.0f);
        val = (val - m2[j]) * rsqrtf(v2[j] + EPSV) * g2[j] + b2[j];
        acc += val;
    }
    v[j] = fmaxf(acc / (float)GRAPHS, 0.f);
    __syncthreads();
    float s = fc1b[j];
    for (int k = 0; k < HID; ++k) s += v[k] * fc1w[k * HID + j];
    u[j] = fmaxf(s, 0.f);
    __syncthreads();
    if (j < CLASSES) {
        float t = fc2b[j];
        for (int k = 0; k < HID; ++k) t += u[k] * fc2w[k * CLASSES + j];
        lg[j] = t;
    }
    __syncthreads();
    if (j < CLASSES) {
        float mx = lg[0];
        for (int c = 1; c < CLASSES; ++c) mx = fmaxf(mx, lg[c]);
        float se = 0.f;
        for (int c = 0; c < CLASSES; ++c) se += expf(lg[c] - mx);
        out[j] = lg[j] - mx - logf(se);
    }
}

extern "C" void kernel_launch(void* const* d_in, const int* in_sizes, int n_in,
                              void* d_out, int out_size, void* d_ws, size_t ws_size,
                              hipStream_t stream) {
    const float* x     = (const float*)d_in[0];
    const int*   ei    = (const int*)d_in[1];
    const int*   ea    = (const int*)d_in[2];
    const int*   batch = (const int*)d_in[3];
    const float* bn1g  = (const float*)d_in[4];
    const float* bn1b  = (const float*)d_in[5];
    const float* bn1m  = (const float*)d_in[6];
    const float* bn1v  = (const float*)d_in[7];
    const float* basis = (const float*)d_in[8];
    const float* comp  = (const float*)d_in[9];
    const float* root  = (const float*)d_in[10];
    const float* bias  = (const float*)d_in[11];
    const float* bn2g  = (const float*)d_in[12];
    const float* bn2b  = (const float*)d_in[13];
    const float* bn2m  = (const float*)d_in[14];
    const float* bn2v  = (const float*)d_in[15];
    const float* fc1w  = (const float*)d_in[16];
    const float* fc1b  = (const float*)d_in[17];
    const float* fc2w  = (const float*)d_in[18];
    const float* fc2b  = (const float*)d_in[19];

    float* ws = (float*)d_ws;
    size_t off = 0;
    unsigned short* wT = (unsigned short*)(ws + off); off += (size_t)LAYERS * NOUT * HID / 2;
    unsigned short* hnb  = (unsigned short*)(ws + off); off += (size_t)NN * HID / 2;
    unsigned short* habf = (unsigned short*)(ws + off); off += (size_t)NN * HID / 2;
    float* deg    = ws + off; off += (size_t)NN * RELS;
    float* psum   = ws + off; off += (size_t)GRAPHS * HID + GRAPHS;
    float* pcnt   = psum + GRAPHS * HID;
    float* escale = ws + off; off += (size_t)NE;
    int* degi     = (int*)(ws + off); off += (size_t)NN;
    int* rowptr   = (int*)(ws + off); off += (size_t)NN + 1;
    int* fillcnt  = (int*)(ws + off); off += (size_t)NN;
    int* bsum     = (int*)(ws + off); off += (size_t)SCAN_NBLK;
    int* epk      = (int*)(ws + off); off += (size_t)NE;
    off = (off + 3) & ~(size_t)3;
    unsigned short* xwb = (unsigned short*)(ws + off);
    off += (size_t)NN * RELS * HID / 2;
    if (ws_size < off * sizeof(float)) return;

    hipMemsetAsync(psum, 0, (GRAPHS * HID + GRAPHS) * sizeof(float), stream);
    hipMemsetAsync(deg, 0, (size_t)NN * RELS * sizeof(float), stream);
    hipMemsetAsync(fillcnt, 0, (size_t)NN * sizeof(int), stream);

    build_wcat<<<(LAYERS * NOUT * HID + 255) / 256, 256, 0, stream>>>(basis, comp, root, wT);
    bn1_kernel<<<(NN * HID + 255) / 256, 256, 0, stream>>>(x, bn1g, bn1b, bn1m, bn1v, habf);

    deg_kernel<<<(NE + 255) / 256, 256, 0, stream>>>(ei, ea, deg);
    invdeg_kernel<<<(NN + 255) / 256, 256, 0, stream>>>(deg, degi);
    scan_partial<<<SCAN_NBLK, 256, 0, stream>>>(degi, rowptr, bsum);
    scan_bsum<<<1, 64, 0, stream>>>(bsum);
    scan_add<<<(NN + 255) / 256, 256, 0, stream>>>(rowptr, bsum);
    fill_kernel<<<(NE + 255) / 256, 256, 0, stream>>>(ei, ea, rowptr, deg, fillcnt, epk, escale);

    for (int l = 0; l < LAYERS; ++l) {
        gemm_mfma<<<(NN + 63) / 64, 256, 0, stream>>>(habf, wT + (size_t)l * NOUT * HID,
                                                      bias + (size_t)l * HID, hnb, xwb);
        aggregate_kernel<<<(NN + 3) / 4, 256, 0, stream>>>(rowptr, epk, escale, xwb, hnb, habf);
    }

    pool_kernel<<<(NN + PCHUNK - 1) / PCHUNK, 256, 0, stream>>>(habf, batch, psum, pcnt);
    head_kernel<<<1, 128, 0, stream>>>(psum, pcnt, bn2g, bn2b, bn2m, bn2v,
                                       fc1w, fc1b, fc2w, fc2b, (float*)d_out);
}